// Round 7
// baseline (705.911 us; speedup 1.0000x reference)
//
#include <hip/hip_runtime.h>
#include <hip/hip_bf16.h>

#define NTOK 4096   // B*N
#define NN   512

typedef __attribute__((ext_vector_type(8))) short bf16x8;
typedef __attribute__((ext_vector_type(4))) short bf16x4;
typedef __attribute__((ext_vector_type(4))) float f32x4;

__device__ __forceinline__ float bf16_to_f(unsigned short u) {
    unsigned int x = ((unsigned int)u) << 16;
    return __builtin_bit_cast(float, x);
}
__device__ __forceinline__ unsigned short f_to_bf16(float f) {
    unsigned int b = __builtin_bit_cast(unsigned int, f);
    return (unsigned short)((b + 0x7fff + ((b >> 16) & 1)) >> 16);
}
__device__ __forceinline__ bf16x8 pack8(float4 a, float4 b) {
    bf16x8 v;
    v[0]=(short)f_to_bf16(a.x); v[1]=(short)f_to_bf16(a.y);
    v[2]=(short)f_to_bf16(a.z); v[3]=(short)f_to_bf16(a.w);
    v[4]=(short)f_to_bf16(b.x); v[5]=(short)f_to_bf16(b.y);
    v[6]=(short)f_to_bf16(b.z); v[7]=(short)f_to_bf16(b.w);
    return v;
}

// ---------------------------------------------------------------------------
__global__ void detect_mask_kernel(const unsigned char* __restrict__ m, int* __restrict__ flag) {
    __shared__ int f;
    if (threadIdx.x == 0) f = 0;
    __syncthreads();
    int any = 0;
    for (int i = threadIdx.x; i < 4096; i += 256) {
        if ((i & 3) != 0 && m[i] != 0) any = 1;
    }
    if (any) atomicOr(&f, 1);
    __syncthreads();
    if (threadIdx.x == 0) *flag = f;   // 1 => byte mask, 0 => int32 mask
}

// ---------------------------------------------------------------------------
__global__ __launch_bounds__(256) void prep_rel16(
    const int* __restrict__ rel, const void* __restrict__ mask,
    const int* __restrict__ flag, short* __restrict__ rel16)
{
    const bool mbyte = (*flag != 0);
    const unsigned char* m8 = (const unsigned char*)mask;
    const int* m32 = (const int*)mask;
    const int i = (blockIdx.x * 256 + threadIdx.x) * 2;
    int2 rv = *(const int2*)(rel + i);
    int ok0, ok1;
    if (mbyte) { ok0 = m8[i]; ok1 = m8[i + 1]; }
    else       { ok0 = (m32[i] != 0); ok1 = (m32[i + 1] != 0); }
    short2 o;
    o.x = ok0 ? (short)rv.x : (short)-1;
    o.y = ok1 ? (short)rv.y : (short)-1;
    *(short2*)(rel16 + i) = o;
}

// ---------------------------------------------------------------------------
__global__ __launch_bounds__(256) void embed_proj_kernel(
    const int* __restrict__ tok, const float* __restrict__ embed,
    const float* __restrict__ W_in, const float* __restrict__ b_in,
    float* __restrict__ x)
{
    __shared__ float emb[8][304];
    __shared__ int tloc[8];
    const int t = threadIdx.x;
    const int r0 = blockIdx.x * 8;
    if (t < 8) tloc[t] = tok[r0 + t];
    __syncthreads();
    for (int i = t; i < 8 * 300; i += 256) {
        int r = i / 300, e = i - r * 300;
        emb[r][e] = embed[(size_t)tloc[r] * 300 + e];
    }
    __syncthreads();
    float acc[8] = {0.f,0.f,0.f,0.f,0.f,0.f,0.f,0.f};
    const int d = t;
    for (int e = 0; e < 300; ++e) {
        float w = W_in[e * 256 + d];
#pragma unroll
        for (int r = 0; r < 8; ++r) acc[r] += emb[r][e] * w;
    }
    const float bb = b_in[d];
#pragma unroll
    for (int r = 0; r < 8; ++r) {
        float o = acc[r] + bb;
        o = o > 0.f ? o : 0.f;
        x[(size_t)(r0 + r) * 256 + d] = o;
    }
}

// ---------------------------------------------------------------------------
// K2a: MFMA bf16 GEMM 64x64 tile (for N=256 outputs), dbuf + reg prefetch.
__global__ __launch_bounds__(256) void gemm_mfma(
    const float* __restrict__ A,
    const float* __restrict__ W0, const float* __restrict__ W1p, const float* __restrict__ W2p,
    int ncPerW, const float* __restrict__ bias,
    float* __restrict__ C, int M, int K, int Nc, int relu)
{
    __shared__ unsigned short As[2][64][40];
    __shared__ unsigned short Bs[2][64][40];

    const int t = threadIdx.x;
    const int lane = t & 63, w = t >> 6;
    const int g = lane >> 4, li = lane & 15;
    const int r0 = blockIdx.y * 64, c0 = blockIdx.x * 64;

    const float* Wp = W0; int cW = c0;
    if (c0 >= 2 * ncPerW)      { Wp = W2p; cW = c0 - 2 * ncPerW; }
    else if (c0 >= ncPerW)     { Wp = W1p; cW = c0 - ncPerW; }

    f32x4 acc[4];
#pragma unroll
    for (int i = 0; i < 4; ++i) acc[i] = (f32x4){0.f, 0.f, 0.f, 0.f};

    const int arow = t >> 2, ad8 = (t & 3) * 8;
    const int bnn = t & 63, bk8 = (t >> 6) * 8;

    const float* ap0 = A + (size_t)(r0 + arow) * K + ad8;
    float4 a0 = *(const float4*)ap0;
    float4 a1 = *(const float4*)(ap0 + 4);
    float wv[8];
#pragma unroll
    for (int j = 0; j < 8; ++j)
        wv[j] = Wp[(size_t)(bk8 + j) * ncPerW + cW + bnn];

    const int nk = K >> 5;
    for (int ki = 0; ki < nk; ++ki) {
        const int cur = ki & 1;
        *(bf16x8*)&As[cur][arow][ad8] = pack8(a0, a1);
        {
            bf16x8 v;
#pragma unroll
            for (int j = 0; j < 8; ++j) v[j] = (short)f_to_bf16(wv[j]);
            *(bf16x8*)&Bs[cur][bnn][bk8] = v;
        }
        if (ki + 1 < nk) {
            const int k0 = (ki + 1) * 32;
            const float* ap = A + (size_t)(r0 + arow) * K + k0 + ad8;
            a0 = *(const float4*)ap;
            a1 = *(const float4*)(ap + 4);
#pragma unroll
            for (int j = 0; j < 8; ++j)
                wv[j] = Wp[(size_t)(k0 + bk8 + j) * ncPerW + cW + bnn];
        }
        __syncthreads();
        bf16x8 af = *(const bf16x8*)&As[cur][16 * w + li][g * 8];
#pragma unroll
        for (int sub = 0; sub < 4; ++sub) {
            bf16x8 bfr = *(const bf16x8*)&Bs[cur][16 * sub + li][g * 8];
            acc[sub] = __builtin_amdgcn_mfma_f32_16x16x32_bf16(af, bfr, acc[sub], 0, 0, 0);
        }
    }
#pragma unroll
    for (int sub = 0; sub < 4; ++sub) {
        int col = c0 + sub * 16 + li;
        float bv = bias ? bias[col] : 0.f;
#pragma unroll
        for (int r = 0; r < 4; ++r) {
            int row = r0 + 16 * w + g * 4 + r;
            float o = acc[sub][r] + bv;
            if (relu) o = fmaxf(o, 0.f);
            C[(size_t)row * Nc + col] = o;
        }
    }
}

// ---------------------------------------------------------------------------
// K2b: MFMA bf16 GEMM 128x64 tile (for wide outputs: QKV, FFN1).
// 4 waves; wave w -> rows 32w..32w+31 (2 chunks), all 64 cols. 8 MFMA/wave/K-step.
__global__ __launch_bounds__(256) void gemm_mfma_128(
    const float* __restrict__ A,
    const float* __restrict__ W0, const float* __restrict__ W1p, const float* __restrict__ W2p,
    int ncPerW, const float* __restrict__ bias,
    float* __restrict__ C, int M, int K, int Nc, int relu)
{
    __shared__ unsigned short As[2][128][40];
    __shared__ unsigned short Bs[2][64][40];

    const int t = threadIdx.x;
    const int lane = t & 63, w = t >> 6;
    const int g = lane >> 4, li = lane & 15;
    const int r0 = blockIdx.y * 128, c0 = blockIdx.x * 64;

    const float* Wp = W0; int cW = c0;
    if (c0 >= 2 * ncPerW)      { Wp = W2p; cW = c0 - 2 * ncPerW; }
    else if (c0 >= ncPerW)     { Wp = W1p; cW = c0 - ncPerW; }

    f32x4 acc[2][4];
#pragma unroll
    for (int i = 0; i < 2; ++i)
#pragma unroll
        for (int j = 0; j < 4; ++j) acc[i][j] = (f32x4){0.f, 0.f, 0.f, 0.f};

    const int arow = t >> 1, ah = (t & 1) * 16;   // A: 128 rows x 2 halves of 16 k
    const int bnn = t & 63, bk8 = (t >> 6) * 8;

    const float* ap0 = A + (size_t)(r0 + arow) * K + ah;
    float4 a0 = *(const float4*)ap0;
    float4 a1 = *(const float4*)(ap0 + 4);
    float4 a2 = *(const float4*)(ap0 + 8);
    float4 a3 = *(const float4*)(ap0 + 12);
    float wv[8];
#pragma unroll
    for (int j = 0; j < 8; ++j)
        wv[j] = Wp[(size_t)(bk8 + j) * ncPerW + cW + bnn];

    const int nk = K >> 5;
    for (int ki = 0; ki < nk; ++ki) {
        const int cur = ki & 1;
        *(bf16x8*)&As[cur][arow][ah]     = pack8(a0, a1);
        *(bf16x8*)&As[cur][arow][ah + 8] = pack8(a2, a3);
        {
            bf16x8 v;
#pragma unroll
            for (int j = 0; j < 8; ++j) v[j] = (short)f_to_bf16(wv[j]);
            *(bf16x8*)&Bs[cur][bnn][bk8] = v;
        }
        if (ki + 1 < nk) {
            const int k0 = (ki + 1) * 32;
            const float* ap = A + (size_t)(r0 + arow) * K + k0 + ah;
            a0 = *(const float4*)ap;
            a1 = *(const float4*)(ap + 4);
            a2 = *(const float4*)(ap + 8);
            a3 = *(const float4*)(ap + 12);
#pragma unroll
            for (int j = 0; j < 8; ++j)
                wv[j] = Wp[(size_t)(k0 + bk8 + j) * ncPerW + cW + bnn];
        }
        __syncthreads();
        bf16x8 af0 = *(const bf16x8*)&As[cur][32 * w + li][g * 8];
        bf16x8 af1 = *(const bf16x8*)&As[cur][32 * w + 16 + li][g * 8];
#pragma unroll
        for (int sub = 0; sub < 4; ++sub) {
            bf16x8 bfr = *(const bf16x8*)&Bs[cur][16 * sub + li][g * 8];
            acc[0][sub] = __builtin_amdgcn_mfma_f32_16x16x32_bf16(af0, bfr, acc[0][sub], 0, 0, 0);
            acc[1][sub] = __builtin_amdgcn_mfma_f32_16x16x32_bf16(af1, bfr, acc[1][sub], 0, 0, 0);
        }
    }
#pragma unroll
    for (int rc = 0; rc < 2; ++rc)
#pragma unroll
    for (int sub = 0; sub < 4; ++sub) {
        int col = c0 + sub * 16 + li;
        float bv = bias ? bias[col] : 0.f;
#pragma unroll
        for (int r = 0; r < 4; ++r) {
            int row = r0 + 32 * w + rc * 16 + g * 4 + r;
            float o = acc[rc][sub][r] + bv;
            if (relu) o = fmaxf(o, 0.f);
            C[(size_t)row * Nc + col] = o;
        }
    }
}

// ---------------------------------------------------------------------------
// K5: qrk[b,h,n,rel] = (q_n * scale) . relk[rel]  (bf16 out). Block=(chunk,h,b).
__global__ __launch_bounds__(256) void qrk_kernel(
    const float* __restrict__ qkv, const float* __restrict__ relk_g,
    unsigned short* __restrict__ qrkg)
{
    const int n0 = blockIdx.x * 64, h = blockIdx.y, b = blockIdx.z;
    const int t = threadIdx.x, lane = t & 63, w = t >> 6;
    const int g = lane >> 4, li = lane & 15;
    const int qrow = 16 * w + g * 4;

    __shared__ unsigned short relk_s[100][40];
    for (int i = t; i < 400; i += 256) {
        int rr = i >> 2, d8 = (i & 3) * 8;
        const float* sp = relk_g + rr * 32 + d8;
        *(bf16x8*)&relk_s[rr][d8] = pack8(*(const float4*)sp, *(const float4*)(sp + 4));
    }
    const float scale = 0.17677669529663687f;
    bf16x8 qf;
    {
        const float* qp = qkv + (size_t)(b * NN + n0 + 16 * w + li) * 768 + h * 32 + g * 8;
        float4 q0 = *(const float4*)qp, q1 = *(const float4*)(qp + 4);
        q0.x *= scale; q0.y *= scale; q0.z *= scale; q0.w *= scale;
        q1.x *= scale; q1.y *= scale; q1.z *= scale; q1.w *= scale;
        qf = pack8(q0, q1);
    }
    __syncthreads();
#pragma unroll
    for (int rc = 0; rc < 7; ++rc) {
        bf16x8 bb = *(const bf16x8*)&relk_s[rc * 16 + li][g * 8];
        f32x4 s = __builtin_amdgcn_mfma_f32_16x16x32_bf16(qf, bb, (f32x4){0.f,0.f,0.f,0.f}, 0, 0, 0);
        int col = rc * 16 + li;
        if (col < 100) {
#pragma unroll
            for (int r = 0; r < 4; ++r)
                qrkg[((size_t)(b * 8 + h) * NN + n0 + qrow + r) * 100 + col] = f_to_bf16(s[r]);
        }
    }
}

// ---------------------------------------------------------------------------
// K3: relation-aware attention, 2-way m-split, 1024 blocks, 4 blocks/CU.
// rel16 + qrk gathered from global (prefetched pipeline); K global->reg;
// V via dbuf LDS; 1 barrier per 32-m tile.
__global__ __launch_bounds__(256, 4) void attn_mfma(
    const float* __restrict__ qkv,       // [BN, 768] (q|k|v)
    const short* __restrict__ rel16,     // [B,N,N]
    const unsigned short* __restrict__ qrkg,  // [B*8][512][100] bf16
    const float* __restrict__ relv_g,    // [100,32]
    float* __restrict__ zpart,           // [2][4096][256]
    float* __restrict__ smpart)          // [2][4096][8]
{
    const int p = blockIdx.x;            // 0..1023
    const int cx = p & 7, idx0 = p >> 3; // idx0 0..127
    const int sg = cx * 8 + (idx0 >> 4); // (b,chunk) slice 0..63, XCD-grouped
    const int hm = idx0 & 15;
    const int h = hm >> 1, ms = hm & 1;
    const int b = sg >> 3, chunk = sg & 7;
    const int n0 = chunk * 64, mbase = ms * 256;

    const int t = threadIdx.x;
    const int lane = t & 63, w = t >> 6;
    const int g = lane >> 4, li = lane & 15;
    const int qrow = 16 * w + g * 4;     // +r

    __shared__ float wrel[64][100];            // 25600 B
    __shared__ union {
        unsigned short relvT[32][136];         // epilogue (8704 B)
        struct {
            unsigned short v_t[2][32][40];     // 5120 B
            unsigned short p_s[4][16][40];     // 5120 B
        } mn;
    } u;                                       // total 35840 B -> 4 blocks/CU

    // ---- prologue
    for (int i = t; i < 6400; i += 256) ((float*)wrel)[i] = 0.f;
    const float scale = 0.17677669529663687f;
    bf16x8 qf;
    {
        const float* qp = qkv + (size_t)(b * NN + n0 + 16 * w + li) * 768 + h * 32 + g * 8;
        float4 q0 = *(const float4*)qp, q1 = *(const float4*)(qp + 4);
        q0.x *= scale; q0.y *= scale; q0.z *= scale; q0.w *= scale;
        q1.x *= scale; q1.y *= scale; q1.z *= scale; q1.w *= scale;
        qf = pack8(q0, q1);
    }
    const short* relrow[4];
    const unsigned short* qgr[4];
#pragma unroll
    for (int r = 0; r < 4; ++r) {
        relrow[r] = rel16 + ((size_t)b * NN + n0 + qrow + r) * NN;
        qgr[r] = qrkg + ((size_t)(b * 8 + h) * NN + n0 + qrow + r) * 100;
    }
    const int vm = t & 31, vdg = t >> 5;
    const size_t kRB = (size_t)(b * NN) * 768 + 256 + h * 32 + g * 8;
    const size_t vRB = (size_t)(b * NN) * 768 + 512 + h * 32 + vdg * 4;

    float4 kbuf[2][4]; float4 vbuf[2];
    short rbuf[2][8]; unsigned short qvb[2][8];
    {   // tile 0: rel -> qrk gather -> K/V
#pragma unroll
        for (int i = 0; i < 8; ++i)
            rbuf[0][i] = relrow[i & 3][mbase + (i >> 2) * 16 + li];
        kbuf[0][0] = *(const float4*)(qkv + kRB + (size_t)(mbase + li) * 768);
        kbuf[0][1] = *(const float4*)(qkv + kRB + (size_t)(mbase + li) * 768 + 4);
        kbuf[0][2] = *(const float4*)(qkv + kRB + (size_t)(mbase + 16 + li) * 768);
        kbuf[0][3] = *(const float4*)(qkv + kRB + (size_t)(mbase + 16 + li) * 768 + 4);
        vbuf[0]    = *(const float4*)(qkv + vRB + (size_t)(mbase + vm) * 768);
#pragma unroll
        for (int i = 0; i < 8; ++i) {
            int rl = rbuf[0][i];
            qvb[0][i] = qgr[i & 3][rl < 0 ? 0 : rl];
        }
    }
    float smacc[4] = {0.f, 0.f, 0.f, 0.f};
    f32x4 zf[2];
    zf[0] = (f32x4){0.f,0.f,0.f,0.f};
    zf[1] = (f32x4){0.f,0.f,0.f,0.f};

    __syncthreads();   // wrel zero visible

    // ---- main loop: 8 tiles of 32 m
#pragma unroll
    for (int tt = 0; tt < 8; ++tt) {
        const int cur = tt & 1, nxt = cur ^ 1;
        {   // V tile write (transposed)
            float4 vv = vbuf[cur];
            u.mn.v_t[cur][vdg * 4 + 0][vm] = f_to_bf16(vv.x);
            u.mn.v_t[cur][vdg * 4 + 1][vm] = f_to_bf16(vv.y);
            u.mn.v_t[cur][vdg * 4 + 2][vm] = f_to_bf16(vv.z);
            u.mn.v_t[cur][vdg * 4 + 3][vm] = f_to_bf16(vv.w);
        }
        // prefetch next tile's rel16 early (needed for qrk gather below)
        if (tt + 1 < 8) {
            const int m0n = mbase + (tt + 1) * 32;
#pragma unroll
            for (int i = 0; i < 8; ++i)
                rbuf[nxt][i] = relrow[i & 3][m0n + (i >> 2) * 16 + li];
        }
        __syncthreads();
        // QK^T from regs
        bf16x8 kf0 = pack8(kbuf[cur][0], kbuf[cur][1]);
        bf16x8 kf1 = pack8(kbuf[cur][2], kbuf[cur][3]);
        // issue next K/V
        if (tt + 1 < 8) {
            const int m0n = mbase + (tt + 1) * 32;
            kbuf[nxt][0] = *(const float4*)(qkv + kRB + (size_t)(m0n + li) * 768);
            kbuf[nxt][1] = *(const float4*)(qkv + kRB + (size_t)(m0n + li) * 768 + 4);
            kbuf[nxt][2] = *(const float4*)(qkv + kRB + (size_t)(m0n + 16 + li) * 768);
            kbuf[nxt][3] = *(const float4*)(qkv + kRB + (size_t)(m0n + 16 + li) * 768 + 4);
            vbuf[nxt]    = *(const float4*)(qkv + vRB + (size_t)(m0n + vm) * 768);
        }
        f32x4 s0 = __builtin_amdgcn_mfma_f32_16x16x32_bf16(qf, kf0, (f32x4){0.f,0.f,0.f,0.f}, 0, 0, 0);
        f32x4 s1 = __builtin_amdgcn_mfma_f32_16x16x32_bf16(qf, kf1, (f32x4){0.f,0.f,0.f,0.f}, 0, 0, 0);
        // scores
        float pr[8];
#pragma unroll
        for (int i = 0; i < 8; ++i) {
            const int r = i & 3;
            const int rl = rbuf[cur][i];
            const float sv = ((i >> 2) ? s1[r] : s0[r]) + bf16_to_f(qvb[cur][i]);
            float pv = 0.f;
            if (rl >= 0) {
                pv = __expf(fminf(sv, 50.f));
                atomicAdd(&wrel[qrow + r][rl], pv);
            }
            smacc[r] += pv;
            pr[i] = pv;
        }
#pragma unroll
        for (int i = 0; i < 8; ++i)
            u.mn.p_s[w][g * 4 + (i & 3)][(i >> 2) * 16 + li] = f_to_bf16(pr[i]);
        // next tile's qrk gathers (rel16 arrived by now)
        if (tt + 1 < 8) {
#pragma unroll
            for (int i = 0; i < 8; ++i) {
                int rl = rbuf[nxt][i];
                qvb[nxt][i] = qgr[i & 3][rl < 0 ? 0 : rl];
            }
        }
        asm volatile("s_waitcnt lgkmcnt(0)" ::: "memory");
        __builtin_amdgcn_sched_barrier(0);
        // PV
        bf16x8 pa = *(const bf16x8*)&u.mn.p_s[w][li][g * 8];
#pragma unroll
        for (int dc = 0; dc < 2; ++dc) {
            bf16x8 vb = *(const bf16x8*)&u.mn.v_t[cur][dc * 16 + li][g * 8];
            zf[dc] = __builtin_amdgcn_mfma_f32_16x16x32_bf16(pa, vb, zf[dc], 0, 0, 0);
        }
    }
    __syncthreads();   // atomics + p_s reads done

    // ---- stage relv transposed; zero rel 100..135
    for (int i = t; i < 32 * 36; i += 256) {
        int d = i / 36, c = 100 + (i - (i / 36) * 36);
        u.relvT[d][c] = 0;
    }
    for (int i = t; i < 400; i += 256) {
        int rr2 = i >> 2, d8 = (i & 3) * 8;
        const float* sp = relv_g + rr2 * 32 + d8;
        float4 s0 = *(const float4*)sp, s1 = *(const float4*)(sp + 4);
        u.relvT[d8 + 0][rr2] = f_to_bf16(s0.x);
        u.relvT[d8 + 1][rr2] = f_to_bf16(s0.y);
        u.relvT[d8 + 2][rr2] = f_to_bf16(s0.z);
        u.relvT[d8 + 3][rr2] = f_to_bf16(s0.w);
        u.relvT[d8 + 4][rr2] = f_to_bf16(s1.x);
        u.relvT[d8 + 5][rr2] = f_to_bf16(s1.y);
        u.relvT[d8 + 6][rr2] = f_to_bf16(s1.z);
        u.relvT[d8 + 7][rr2] = f_to_bf16(s1.w);
    }
    __syncthreads();

    // ---- z += wrel_partial @ relv
#pragma unroll
    for (int kc = 0; kc < 4; ++kc) {
        const int kbase = kc * 32 + g * 8;
        const float* wp = &wrel[16 * w + li][0];
        bf16x8 af;
#pragma unroll
        for (int j = 0; j < 8; ++j) {
            int id = kbase + j;
            float val = (id < 100) ? wp[id] : 0.f;
            af[j] = (short)f_to_bf16(val);
        }
#pragma unroll
        for (int dc = 0; dc < 2; ++dc) {
            bf16x8 vb = *(const bf16x8*)&u.relvT[dc * 16 + li][kbase];
            zf[dc] = __builtin_amdgcn_mfma_f32_16x16x32_bf16(af, vb, zf[dc], 0, 0, 0);
        }
    }

    // ---- sm reduce over 16 m-lanes; write partials
#pragma unroll
    for (int r = 0; r < 4; ++r) {
        smacc[r] += __shfl_xor(smacc[r], 1, 64);
        smacc[r] += __shfl_xor(smacc[r], 2, 64);
        smacc[r] += __shfl_xor(smacc[r], 4, 64);
        smacc[r] += __shfl_xor(smacc[r], 8, 64);
    }
#pragma unroll
    for (int r = 0; r < 4; ++r) {
        const int row = b * NN + n0 + qrow + r;
        size_t ob = (size_t)ms * 1048576 + (size_t)row * 256 + h * 32;
#pragma unroll
        for (int dc = 0; dc < 2; ++dc)
            zpart[ob + dc * 16 + li] = zf[dc][r];
        if (li == 0)
            smpart[(size_t)ms * 32768 + (size_t)row * 8 + h] = smacc[r];
    }
}

// ---------------------------------------------------------------------------
__global__ __launch_bounds__(256) void combine_kernel(
    const float* __restrict__ zpart, const float* __restrict__ smpart,
    float* __restrict__ z)
{
    const int t = threadIdx.x;
    const int wi = t >> 6, lane = t & 63;
    const int row = blockIdx.x * 4 + wi;
    const int h = lane >> 3;
    float den = 0.f;
    float4 acc = make_float4(0.f, 0.f, 0.f, 0.f);
#pragma unroll
    for (int s = 0; s < 2; ++s) {
        den += smpart[(size_t)s * 32768 + (size_t)row * 8 + h];
        float4 v = *(const float4*)(zpart + (size_t)s * 1048576 + (size_t)row * 256 + lane * 4);
        acc.x += v.x; acc.y += v.y; acc.z += v.z; acc.w += v.w;
    }
    const float inv = 1.f / den;
    acc.x *= inv; acc.y *= inv; acc.z *= inv; acc.w *= inv;
    *(float4*)(z + (size_t)row * 256 + lane * 4) = acc;
}

// ---------------------------------------------------------------------------
__global__ __launch_bounds__(256) void ln_kernel(
    const float* __restrict__ xin, const float* __restrict__ y,
    const float* __restrict__ g, const float* __restrict__ bsh,
    float* __restrict__ xout)
{
    const int t = threadIdx.x;
    const int w = t >> 6, lane = t & 63;
    const size_t row = (size_t)blockIdx.x * 4 + w;
    const float4 xv = *(const float4*)(xin + row * 256 + lane * 4);
    const float4 yv = *(const float4*)(y + row * 256 + lane * 4);
    float4 sv;
    sv.x = xv.x + yv.x; sv.y = xv.y + yv.y; sv.z = xv.z + yv.z; sv.w = xv.w + yv.w;
    float sum = sv.x + sv.y + sv.z + sv.w;
    float sq  = sv.x * sv.x + sv.y * sv.y + sv.z * sv.z + sv.w * sv.w;
#pragma unroll
    for (int off = 1; off < 64; off <<= 1) {
        sum += __shfl_xor(sum, off, 64);
        sq  += __shfl_xor(sq, off, 64);
    }
    const float mu = sum * (1.f / 256.f);
    const float var = sq * (1.f / 256.f) - mu * mu;
    const float rs = rsqrtf(var + 1e-5f);
    const float4 gv = *(const float4*)(g + lane * 4);
    const float4 bv = *(const float4*)(bsh + lane * 4);
    float4 o;
    o.x = (sv.x - mu) * rs * gv.x + bv.x;
    o.y = (sv.y - mu) * rs * gv.y + bv.y;
    o.z = (sv.z - mu) * rs * gv.z + bv.z;
    o.w = (sv.w - mu) * rs * gv.w + bv.w;
    *(float4*)(xout + row * 256 + lane * 4) = o;
}

// ---------------------------------------------------------------------------
extern "C" void kernel_launch(void* const* d_in, const int* in_sizes, int n_in,
                              void* d_out, int out_size, void* d_ws, size_t ws_size,
                              hipStream_t stream)
{
    (void)in_sizes; (void)n_in; (void)out_size;
    const int*   tok   = (const int*)d_in[0];
    const int*   rel   = (const int*)d_in[1];
    const void*  mask  = d_in[2];
    const float* embed = (const float*)d_in[3];
    const float* W_in  = (const float*)d_in[4];
    const float* b_in  = (const float*)d_in[5];
    const float* Wq    = (const float*)d_in[6];
    const float* Wk    = (const float*)d_in[7];
    const float* Wv    = (const float*)d_in[8];
    const float* Wo    = (const float*)d_in[9];
    const float* ln1g  = (const float*)d_in[10];
    const float* ln1b  = (const float*)d_in[11];
    const float* ln2g  = (const float*)d_in[12];
    const float* ln2b  = (const float*)d_in[13];
    const float* W1    = (const float*)d_in[14];
    const float* b1    = (const float*)d_in[15];
    const float* W2    = (const float*)d_in[16];
    const float* b2    = (const float*)d_in[17];
    const float* relk  = (const float*)d_in[18];
    const float* relv  = (const float*)d_in[19];
    const float* Wout  = (const float*)d_in[20];
    const float* bout  = (const float*)d_in[21];
    float* out = (float*)d_out;

    float* ws  = (float*)d_ws;
    float* x   = ws;                       // 1M floats
    float* z   = ws + (1u << 20);          // 1M
    float* zo  = ws + 2u * (1u << 20);     // 1M (smpart during attn)
    float* qkv = ws + 3u * (1u << 20);     // 3M
    float* hb  = ws + 6u * (1u << 20);     // 4M: zpart (2M) + qrkg (1.64M) during attn; FFN hidden later

    const bool roomy = ws_size >= ((size_t)45 << 20);
    short* rel16 = roomy ? (short*)(ws + 10u * (1u << 20)) : (short*)z;
    int*   flag  = (int*)(ws + (roomy ? 11u : 10u) * (1u << 20));
    float* zpart = hb;                                     // [2][4096][256]
    unsigned short* qrkg = (unsigned short*)(hb + 2u * (1u << 20));  // [8*8][512][100] bf16
    float* smpart = zo;                                    // [2][4096][8]

    detect_mask_kernel<<<1, 256, 0, stream>>>((const unsigned char*)mask, flag);
    if (roomy)
        prep_rel16<<<4096, 256, 0, stream>>>(rel, mask, flag, rel16);
    embed_proj_kernel<<<512, 256, 0, stream>>>(tok, embed, W_in, b_in, x);

    for (int l = 0; l < 4; ++l) {
        const float* wq = Wq + (size_t)l * 65536;
        const float* wk = Wk + (size_t)l * 65536;
        const float* wv = Wv + (size_t)l * 65536;
        const float* wo = Wo + (size_t)l * 65536;
        const float* w1 = W1 + (size_t)l * 262144;
        const float* w2 = W2 + (size_t)l * 262144;

        if (!roomy)
            prep_rel16<<<4096, 256, 0, stream>>>(rel, mask, flag, rel16);

        gemm_mfma_128<<<dim3(12, 32), 256, 0, stream>>>(x, wq, wk, wv, 256, nullptr,
                                                        qkv, NTOK, 256, 768, 0);
        qrk_kernel<<<dim3(8, 8, 8), 256, 0, stream>>>(qkv, relk, qrkg);
        attn_mfma<<<1024, 256, 0, stream>>>(qkv, rel16, qrkg, relv, zpart, smpart);
        combine_kernel<<<1024, 256, 0, stream>>>(zpart, smpart, z);
        gemm_mfma<<<dim3(4, 64), 256, 0, stream>>>(z, wo, wo, wo, 256, nullptr,
                                                   zo, NTOK, 256, 256, 0);
        ln_kernel<<<1024, 256, 0, stream>>>(x, zo, ln1g + l * 256, ln1b + l * 256, x);
        gemm_mfma_128<<<dim3(16, 32), 256, 0, stream>>>(x, w1, w1, w1, 1024, b1 + l * 1024,
                                                        hb, NTOK, 256, 1024, 1);
        gemm_mfma<<<dim3(4, 64), 256, 0, stream>>>(hb, w2, w2, w2, 256, b2 + l * 256,
                                                   zo, NTOK, 1024, 256, 0);
        ln_kernel<<<1024, 256, 0, stream>>>(x, zo, ln2g + l * 256, ln2b + l * 256, x);
    }
    gemm_mfma<<<dim3(4, 64), 256, 0, stream>>>(x, Wout, Wout, Wout, 256, bout,
                                               out, NTOK, 256, 256, 0);
}

// Round 9
// 646.759 us; speedup vs baseline: 1.0915x; 1.0915x over previous
//
#include <hip/hip_runtime.h>
#include <hip/hip_bf16.h>

#define NTOK 4096   // B*N
#define NN   512

typedef __attribute__((ext_vector_type(8))) short bf16x8;
typedef __attribute__((ext_vector_type(4))) float f32x4;
typedef __attribute__((ext_vector_type(4))) unsigned short u16x4;

__device__ __forceinline__ float bf16_to_f(unsigned short u) {
    unsigned int x = ((unsigned int)u) << 16;
    return __builtin_bit_cast(float, x);
}
__device__ __forceinline__ unsigned short f_to_bf16(float f) {
    unsigned int b = __builtin_bit_cast(unsigned int, f);
    return (unsigned short)((b + 0x7fff + ((b >> 16) & 1)) >> 16);
}
__device__ __forceinline__ bf16x8 pack8(float4 a, float4 b) {
    bf16x8 v;
    v[0]=(short)f_to_bf16(a.x); v[1]=(short)f_to_bf16(a.y);
    v[2]=(short)f_to_bf16(a.z); v[3]=(short)f_to_bf16(a.w);
    v[4]=(short)f_to_bf16(b.x); v[5]=(short)f_to_bf16(b.y);
    v[6]=(short)f_to_bf16(b.z); v[7]=(short)f_to_bf16(b.w);
    return v;
}

// ---------------------------------------------------------------------------
__global__ void detect_mask_kernel(const unsigned char* __restrict__ m, int* __restrict__ flag) {
    __shared__ int f;
    if (threadIdx.x == 0) f = 0;
    __syncthreads();
    int any = 0;
    for (int i = threadIdx.x; i < 4096; i += 256) {
        if ((i & 3) != 0 && m[i] != 0) any = 1;
    }
    if (any) atomicOr(&f, 1);
    __syncthreads();
    if (threadIdx.x == 0) *flag = f;   // 1 => byte mask, 0 => int32 mask
}

// ---------------------------------------------------------------------------
__global__ __launch_bounds__(256) void prep_rel16(
    const int* __restrict__ rel, const void* __restrict__ mask,
    const int* __restrict__ flag, short* __restrict__ rel16)
{
    const bool mbyte = (*flag != 0);
    const unsigned char* m8 = (const unsigned char*)mask;
    const int* m32 = (const int*)mask;
    const int i = (blockIdx.x * 256 + threadIdx.x) * 2;
    int2 rv = *(const int2*)(rel + i);
    int ok0, ok1;
    if (mbyte) { ok0 = m8[i]; ok1 = m8[i + 1]; }
    else       { ok0 = (m32[i] != 0); ok1 = (m32[i + 1] != 0); }
    short2 o;
    o.x = ok0 ? (short)rv.x : (short)-1;
    o.y = ok1 ? (short)rv.y : (short)-1;
    *(short2*)(rel16 + i) = o;
}

// ---------------------------------------------------------------------------
// Transpose-cast: out[n][k] = bf16(in[k][n] * sc), 256x256 weights (+Wout).
__global__ __launch_bounds__(256) void tcast256(
    const float* __restrict__ Wq, const float* __restrict__ Wk,
    const float* __restrict__ Wv, const float* __restrict__ Wo,
    const float* __restrict__ Wout, unsigned short* __restrict__ wt,
    int nL, float scale)
{
    const int z = blockIdx.z;
    const float* src; unsigned short* dst; float sc = 1.f;
    if (z >= nL * 4) {
        src = Wout; dst = wt + (size_t)nL * 786432;
    } else {
        const int l = z >> 2, which = z & 3;
        if      (which == 0) { src = Wq + (size_t)l * 65536; sc = scale; }
        else if (which == 1) { src = Wk + (size_t)l * 65536; }
        else if (which == 2) { src = Wv + (size_t)l * 65536; }
        else                 { src = Wo + (size_t)l * 65536; }
        dst = wt + (size_t)l * 786432 + which * 65536;
    }
    __shared__ float tile[32][33];
    const int t = threadIdx.x, tx = t & 31, ty = t >> 5;
    const int n0 = blockIdx.x * 32, k0 = blockIdx.y * 32;
#pragma unroll
    for (int p = 0; p < 4; ++p)
        tile[ty + p * 8][tx] = src[(size_t)(k0 + ty + p * 8) * 256 + n0 + tx];
    __syncthreads();
#pragma unroll
    for (int p = 0; p < 4; ++p)
        dst[(size_t)(n0 + ty + p * 8) * 256 + k0 + tx] = f_to_bf16(tile[tx][ty + p * 8] * sc);
}

// Generic transpose-cast for W1/W2 (z = layer index).
__global__ __launch_bounds__(256) void tcastKN(
    const float* __restrict__ in, unsigned short* __restrict__ out,
    int K, int N, long inStride, long outStride)
{
    in  += (size_t)blockIdx.z * inStride;
    out += (size_t)blockIdx.z * outStride;
    __shared__ float tile[32][33];
    const int t = threadIdx.x, tx = t & 31, ty = t >> 5;
    const int n0 = blockIdx.x * 32, k0 = blockIdx.y * 32;
#pragma unroll
    for (int p = 0; p < 4; ++p)
        tile[ty + p * 8][tx] = in[(size_t)(k0 + ty + p * 8) * N + n0 + tx];
    __syncthreads();
#pragma unroll
    for (int p = 0; p < 4; ++p)
        out[(size_t)(n0 + ty + p * 8) * K + k0 + tx] = f_to_bf16(tile[tx][ty + p * 8]);
}

// ---------------------------------------------------------------------------
__global__ __launch_bounds__(256) void embed_proj_kernel(
    const int* __restrict__ tok, const float* __restrict__ embed,
    const float* __restrict__ W_in, const float* __restrict__ b_in,
    float* __restrict__ x, unsigned short* __restrict__ xh)
{
    __shared__ float emb[8][304];
    __shared__ int tloc[8];
    const int t = threadIdx.x;
    const int r0 = blockIdx.x * 8;
    if (t < 8) tloc[t] = tok[r0 + t];
    __syncthreads();
    for (int i = t; i < 8 * 300; i += 256) {
        int r = i / 300, e = i - r * 300;
        emb[r][e] = embed[(size_t)tloc[r] * 300 + e];
    }
    __syncthreads();
    float acc[8] = {0.f,0.f,0.f,0.f,0.f,0.f,0.f,0.f};
    const int d = t;
    for (int e = 0; e < 300; ++e) {
        float w = W_in[e * 256 + d];
#pragma unroll
        for (int r = 0; r < 8; ++r) acc[r] += emb[r][e] * w;
    }
    const float bb = b_in[d];
#pragma unroll
    for (int r = 0; r < 8; ++r) {
        float o = acc[r] + bb;
        o = o > 0.f ? o : 0.f;
        x[(size_t)(r0 + r) * 256 + d] = o;
        xh[(size_t)(r0 + r) * 256 + d] = f_to_bf16(o);
    }
}

// ---------------------------------------------------------------------------
// bf16 GEMM, 64x64 tile. A bf16 [M][K], WT bf16 [Nc][K]. Out f32 (Cf) or bf16 (Ch).
__global__ __launch_bounds__(256) void gemm_bf16_64(
    const unsigned short* __restrict__ A, const unsigned short* __restrict__ WT,
    const float* __restrict__ bias, float* __restrict__ Cf, unsigned short* __restrict__ Ch,
    int M, int K, int Nc, int relu)
{
    __shared__ unsigned short As[2][64][40];
    __shared__ unsigned short Bs[2][64][40];
    const int t = threadIdx.x;
    const int lane = t & 63, w = t >> 6;
    const int g = lane >> 4, li = lane & 15;
    const int r0 = blockIdx.y * 64, c0 = blockIdx.x * 64;

    f32x4 acc[4];
#pragma unroll
    for (int i = 0; i < 4; ++i) acc[i] = (f32x4){0.f,0.f,0.f,0.f};

    const int arow = t >> 2, ad8 = (t & 3) * 8;

    bf16x8 a0 = *(const bf16x8*)(A  + (size_t)(r0 + arow) * K + ad8);
    bf16x8 b0 = *(const bf16x8*)(WT + (size_t)(c0 + arow) * K + ad8);

    const int nk = K >> 5;
    for (int ki = 0; ki < nk; ++ki) {
        const int cur = ki & 1;
        *(bf16x8*)&As[cur][arow][ad8] = a0;
        *(bf16x8*)&Bs[cur][arow][ad8] = b0;
        if (ki + 1 < nk) {
            const int k0 = (ki + 1) * 32;
            a0 = *(const bf16x8*)(A  + (size_t)(r0 + arow) * K + k0 + ad8);
            b0 = *(const bf16x8*)(WT + (size_t)(c0 + arow) * K + k0 + ad8);
        }
        __syncthreads();
        bf16x8 af = *(const bf16x8*)&As[cur][16 * w + li][g * 8];
#pragma unroll
        for (int sub = 0; sub < 4; ++sub) {
            bf16x8 bfr = *(const bf16x8*)&Bs[cur][16 * sub + li][g * 8];
            acc[sub] = __builtin_amdgcn_mfma_f32_16x16x32_bf16(af, bfr, acc[sub], 0, 0, 0);
        }
    }
#pragma unroll
    for (int sub = 0; sub < 4; ++sub) {
        int col = c0 + sub * 16 + li;
        float bv = bias ? bias[col] : 0.f;
#pragma unroll
        for (int r = 0; r < 4; ++r) {
            int row = r0 + 16 * w + g * 4 + r;
            float o = acc[sub][r] + bv;
            if (relu) o = fmaxf(o, 0.f);
            if (Ch) Ch[(size_t)row * Nc + col] = f_to_bf16(o);
            else    Cf[(size_t)row * Nc + col] = o;
        }
    }
}

// ---------------------------------------------------------------------------
// bf16 GEMM, 128x64 tile (QKV, FFN1).
__global__ __launch_bounds__(256) void gemm_bf16_128(
    const unsigned short* __restrict__ A, const unsigned short* __restrict__ WT,
    const float* __restrict__ bias, float* __restrict__ Cf, unsigned short* __restrict__ Ch,
    int M, int K, int Nc, int relu)
{
    __shared__ unsigned short As[2][128][40];
    __shared__ unsigned short Bs[2][64][40];
    const int t = threadIdx.x;
    const int lane = t & 63, w = t >> 6;
    const int g = lane >> 4, li = lane & 15;
    const int r0 = blockIdx.y * 128, c0 = blockIdx.x * 64;

    f32x4 acc[2][4];
#pragma unroll
    for (int i = 0; i < 2; ++i)
#pragma unroll
        for (int j = 0; j < 4; ++j) acc[i][j] = (f32x4){0.f,0.f,0.f,0.f};

    const int arow = t >> 1, ah = (t & 1) * 16;
    const int bcol = t >> 2, bk8 = (t & 3) * 8;

    bf16x8 a0 = *(const bf16x8*)(A + (size_t)(r0 + arow) * K + ah);
    bf16x8 a1 = *(const bf16x8*)(A + (size_t)(r0 + arow) * K + ah + 8);
    bf16x8 b0 = *(const bf16x8*)(WT + (size_t)(c0 + bcol) * K + bk8);

    const int nk = K >> 5;
    for (int ki = 0; ki < nk; ++ki) {
        const int cur = ki & 1;
        *(bf16x8*)&As[cur][arow][ah]     = a0;
        *(bf16x8*)&As[cur][arow][ah + 8] = a1;
        *(bf16x8*)&Bs[cur][bcol][bk8]    = b0;
        if (ki + 1 < nk) {
            const int k0 = (ki + 1) * 32;
            a0 = *(const bf16x8*)(A + (size_t)(r0 + arow) * K + k0 + ah);
            a1 = *(const bf16x8*)(A + (size_t)(r0 + arow) * K + k0 + ah + 8);
            b0 = *(const bf16x8*)(WT + (size_t)(c0 + bcol) * K + k0 + bk8);
        }
        __syncthreads();
        bf16x8 af0 = *(const bf16x8*)&As[cur][32 * w + li][g * 8];
        bf16x8 af1 = *(const bf16x8*)&As[cur][32 * w + 16 + li][g * 8];
#pragma unroll
        for (int sub = 0; sub < 4; ++sub) {
            bf16x8 bfr = *(const bf16x8*)&Bs[cur][16 * sub + li][g * 8];
            acc[0][sub] = __builtin_amdgcn_mfma_f32_16x16x32_bf16(af0, bfr, acc[0][sub], 0, 0, 0);
            acc[1][sub] = __builtin_amdgcn_mfma_f32_16x16x32_bf16(af1, bfr, acc[1][sub], 0, 0, 0);
        }
    }
#pragma unroll
    for (int rc = 0; rc < 2; ++rc)
#pragma unroll
    for (int sub = 0; sub < 4; ++sub) {
        int col = c0 + sub * 16 + li;
        float bv = bias ? bias[col] : 0.f;
#pragma unroll
        for (int r = 0; r < 4; ++r) {
            int row = r0 + 32 * w + rc * 16 + g * 4 + r;
            float o = acc[rc][sub][r] + bv;
            if (relu) o = fmaxf(o, 0.f);
            if (Ch) Ch[(size_t)row * Nc + col] = f_to_bf16(o);
            else    Cf[(size_t)row * Nc + col] = o;
        }
    }
}

// ---------------------------------------------------------------------------
// qrk[b,h,n,rel] = q_n . relk[rel]  (q pre-scaled in Wq cast). Block=(chunk,h,b).
__global__ __launch_bounds__(256) void qrk_kernel(
    const unsigned short* __restrict__ qkvh, const float* __restrict__ relk_g,
    unsigned short* __restrict__ qrkg)
{
    const int n0 = blockIdx.x * 64, h = blockIdx.y, b = blockIdx.z;
    const int t = threadIdx.x, lane = t & 63, w = t >> 6;
    const int g = lane >> 4, li = lane & 15;
    const int qrow = 16 * w + g * 4;

    __shared__ unsigned short relk_s[100][40];
    for (int i = t; i < 400; i += 256) {
        int rr = i >> 2, d8 = (i & 3) * 8;
        const float* sp = relk_g + rr * 32 + d8;
        *(bf16x8*)&relk_s[rr][d8] = pack8(*(const float4*)sp, *(const float4*)(sp + 4));
    }
    bf16x8 qf = *(const bf16x8*)(qkvh + (size_t)(b * NN + n0 + 16 * w + li) * 768 + h * 32 + g * 8);
    __syncthreads();
#pragma unroll
    for (int rc = 0; rc < 7; ++rc) {
        bf16x8 bb = *(const bf16x8*)&relk_s[rc * 16 + li][g * 8];
        f32x4 s = __builtin_amdgcn_mfma_f32_16x16x32_bf16(qf, bb, (f32x4){0.f,0.f,0.f,0.f}, 0, 0, 0);
        int col = rc * 16 + li;
        if (col < 100) {
#pragma unroll
            for (int r = 0; r < 4; ++r)
                qrkg[((size_t)(b * 8 + h) * NN + n0 + qrow + r) * 100 + col] = f_to_bf16(s[r]);
        }
    }
}

// ---------------------------------------------------------------------------
// Attention: 2-way m-split, bf16 qkv, qrk bulk-staged to LDS (no global gathers).
__global__ __launch_bounds__(256, 3) void attn_mfma(
    const unsigned short* __restrict__ qkvh,  // [4096][768] bf16, q pre-scaled
    const short* __restrict__ rel16,
    const unsigned short* __restrict__ qrkg,  // [64][512][100] bf16
    const float* __restrict__ relv_g,
    float* __restrict__ zpart, float* __restrict__ smpart)
{
    const int p = blockIdx.x;            // 0..1023
    const int cx = p & 7, idx0 = p >> 3;
    const int sg = cx * 8 + (idx0 >> 4); // (b,chunk) slice, XCD-grouped
    const int hm = idx0 & 15;
    const int h = hm >> 1, ms = hm & 1;
    const int b = sg >> 3, chunk = sg & 7;
    const int n0 = chunk * 64, mbase = ms * 256;

    const int t = threadIdx.x;
    const int lane = t & 63, w = t >> 6;
    const int g = lane >> 4, li = lane & 15;
    const int qrow = 16 * w + g * 4;

    __shared__ float wrel[64][100];            // 25600 B
    __shared__ unsigned short qrk_lds[64][100];// 12800 B
    __shared__ union {
        unsigned short relvT[32][136];         // 8704 B (epilogue)
        struct {
            unsigned short v_t[2][32][40];     // 5120 B
            unsigned short p_s[4][16][40];     // 5120 B
        } mn;
    } u;                                       // 48640 B total -> 3 blocks/CU

    // prologue: zero wrel, bulk-stage qrk slice (64 rows x 50 dwords), load Q frag
    for (int i = t; i < 6400; i += 256) ((float*)wrel)[i] = 0.f;
    {
        const unsigned short* qsrc = qrkg + ((size_t)(b * 8 + h) * NN + n0) * 100;
        for (int i = t; i < 3200; i += 256) {
            int row = i / 50, off = (i - row * 50) * 2;
            *(unsigned int*)&qrk_lds[row][off] =
                *(const unsigned int*)(qsrc + (size_t)row * 100 + off);
        }
    }
    bf16x8 qf = *(const bf16x8*)(qkvh + (size_t)(b * NN + n0 + 16 * w + li) * 768 + h * 32 + g * 8);

    const short* relrow[4];
#pragma unroll
    for (int r = 0; r < 4; ++r)
        relrow[r] = rel16 + ((size_t)b * NN + n0 + qrow + r) * NN;
    const int vm = t & 31, vdg = t >> 5;
    const size_t kRB = (size_t)(b * NN) * 768 + 256 + h * 32 + g * 8;
    const size_t vRB = (size_t)(b * NN) * 768 + 512 + h * 32 + vdg * 4;

    bf16x8 kbuf[2][2]; u16x4 vbuf[2]; short rbuf[2][8];
#pragma unroll
    for (int i = 0; i < 8; ++i)
        rbuf[0][i] = relrow[i & 3][mbase + (i >> 2) * 16 + li];
    kbuf[0][0] = *(const bf16x8*)(qkvh + kRB + (size_t)(mbase + li) * 768);
    kbuf[0][1] = *(const bf16x8*)(qkvh + kRB + (size_t)(mbase + 16 + li) * 768);
    vbuf[0]    = *(const u16x4*)(qkvh + vRB + (size_t)(mbase + vm) * 768);

    float smacc[4] = {0.f, 0.f, 0.f, 0.f};
    f32x4 zf[2];
    zf[0] = (f32x4){0.f,0.f,0.f,0.f};
    zf[1] = (f32x4){0.f,0.f,0.f,0.f};

    __syncthreads();

    // main loop: 8 tiles of 32 m, one barrier per tile
#pragma unroll
    for (int tt = 0; tt < 8; ++tt) {
        const int cur = tt & 1, nxt = cur ^ 1;
        u.mn.v_t[cur][vdg * 4 + 0][vm] = vbuf[cur][0];
        u.mn.v_t[cur][vdg * 4 + 1][vm] = vbuf[cur][1];
        u.mn.v_t[cur][vdg * 4 + 2][vm] = vbuf[cur][2];
        u.mn.v_t[cur][vdg * 4 + 3][vm] = vbuf[cur][3];
        if (tt + 1 < 8) {
            const int m0n = mbase + (tt + 1) * 32;
#pragma unroll
            for (int i = 0; i < 8; ++i)
                rbuf[nxt][i] = relrow[i & 3][m0n + (i >> 2) * 16 + li];
        }
        __syncthreads();
        bf16x8 kf0 = kbuf[cur][0], kf1 = kbuf[cur][1];
        if (tt + 1 < 8) {   // issue next K/V early (hide under compute)
            const int m0n = mbase + (tt + 1) * 32;
            kbuf[nxt][0] = *(const bf16x8*)(qkvh + kRB + (size_t)(m0n + li) * 768);
            kbuf[nxt][1] = *(const bf16x8*)(qkvh + kRB + (size_t)(m0n + 16 + li) * 768);
            vbuf[nxt]    = *(const u16x4*)(qkvh + vRB + (size_t)(m0n + vm) * 768);
        }
        f32x4 s0 = __builtin_amdgcn_mfma_f32_16x16x32_bf16(qf, kf0, (f32x4){0.f,0.f,0.f,0.f}, 0, 0, 0);
        f32x4 s1 = __builtin_amdgcn_mfma_f32_16x16x32_bf16(qf, kf1, (f32x4){0.f,0.f,0.f,0.f}, 0, 0, 0);
        float pr[8];
#pragma unroll
        for (int i = 0; i < 8; ++i) {
            const int r = i & 3;
            const int rl = rbuf[cur][i];
            const float qadd = bf16_to_f(qrk_lds[qrow + r][rl < 0 ? 0 : rl]);
            const float sv = ((i >> 2) ? s1[r] : s0[r]) + qadd;
            float pv = 0.f;
            if (rl >= 0) {
                pv = __expf(fminf(sv, 50.f));
                atomicAdd(&wrel[qrow + r][rl], pv);
            }
            smacc[r] += pv;
            pr[i] = pv;
        }
#pragma unroll
        for (int i = 0; i < 8; ++i)
            u.mn.p_s[w][g * 4 + (i & 3)][(i >> 2) * 16 + li] = f_to_bf16(pr[i]);
        asm volatile("s_waitcnt lgkmcnt(0)" ::: "memory");
        __builtin_amdgcn_sched_barrier(0);
        bf16x8 pa = *(const bf16x8*)&u.mn.p_s[w][li][g * 8];
#pragma unroll
        for (int dc = 0; dc < 2; ++dc) {
            bf16x8 vb = *(const bf16x8*)&u.mn.v_t[cur][dc * 16 + li][g * 8];
            zf[dc] = __builtin_amdgcn_mfma_f32_16x16x32_bf16(pa, vb, zf[dc], 0, 0, 0);
        }
    }
    __syncthreads();

    // epilogue: stage relv^T, add wrel @ relv, write partials
    for (int i = t; i < 32 * 36; i += 256) {
        int d = i / 36, c = 100 + (i - (i / 36) * 36);
        u.relvT[d][c] = 0;
    }
    for (int i = t; i < 400; i += 256) {
        int rr2 = i >> 2, d8 = (i & 3) * 8;
        const float* sp = relv_g + rr2 * 32 + d8;
        float4 s0 = *(const float4*)sp, s1 = *(const float4*)(sp + 4);
        u.relvT[d8 + 0][rr2] = f_to_bf16(s0.x);
        u.relvT[d8 + 1][rr2] = f_to_bf16(s0.y);
        u.relvT[d8 + 2][rr2] = f_to_bf16(s0.z);
        u.relvT[d8 + 3][rr2] = f_to_bf16(s0.w);
        u.relvT[d8 + 4][rr2] = f_to_bf16(s1.x);
        u.relvT[d8 + 5][rr2] = f_to_bf16(s1.y);
        u.relvT[d8 + 6][rr2] = f_to_bf16(s1.z);
        u.relvT[d8 + 7][rr2] = f_to_bf16(s1.w);
    }
    __syncthreads();
#pragma unroll
    for (int kc = 0; kc < 4; ++kc) {
        const int kbase = kc * 32 + g * 8;
        const float* wp = &wrel[16 * w + li][0];
        bf16x8 af;
#pragma unroll
        for (int j = 0; j < 8; ++j) {
            int id = kbase + j;
            float val = (id < 100) ? wp[id] : 0.f;
            af[j] = (short)f_to_bf16(val);
        }
#pragma unroll
        for (int dc = 0; dc < 2; ++dc) {
            bf16x8 vb = *(const bf16x8*)&u.relvT[dc * 16 + li][kbase];
            zf[dc] = __builtin_amdgcn_mfma_f32_16x16x32_bf16(af, vb, zf[dc], 0, 0, 0);
        }
    }
#pragma unroll
    for (int r = 0; r < 4; ++r) {
        smacc[r] += __shfl_xor(smacc[r], 1, 64);
        smacc[r] += __shfl_xor(smacc[r], 2, 64);
        smacc[r] += __shfl_xor(smacc[r], 4, 64);
        smacc[r] += __shfl_xor(smacc[r], 8, 64);
    }
#pragma unroll
    for (int r = 0; r < 4; ++r) {
        const int row = b * NN + n0 + qrow + r;
        size_t ob = (size_t)ms * 1048576 + (size_t)row * 256 + h * 32;
#pragma unroll
        for (int dc = 0; dc < 2; ++dc)
            zpart[ob + dc * 16 + li] = zf[dc][r];
        if (li == 0)
            smpart[(size_t)ms * 32768 + (size_t)row * 8 + h] = smacc[r];
    }
}

// ---------------------------------------------------------------------------
__global__ __launch_bounds__(256) void combine_kernel(
    const float* __restrict__ zpart, const float* __restrict__ smpart,
    unsigned short* __restrict__ zbf)
{
    const int t = threadIdx.x;
    const int wi = t >> 6, lane = t & 63;
    const int row = blockIdx.x * 4 + wi;
    const int h = lane >> 3;
    float den = 0.f;
    float4 acc = make_float4(0.f, 0.f, 0.f, 0.f);
#pragma unroll
    for (int s = 0; s < 2; ++s) {
        den += smpart[(size_t)s * 32768 + (size_t)row * 8 + h];
        float4 v = *(const float4*)(zpart + (size_t)s * 1048576 + (size_t)row * 256 + lane * 4);
        acc.x += v.x; acc.y += v.y; acc.z += v.z; acc.w += v.w;
    }
    const float inv = 1.f / den;
    u16x4 oh;
    oh[0] = f_to_bf16(acc.x * inv);
    oh[1] = f_to_bf16(acc.y * inv);
    oh[2] = f_to_bf16(acc.z * inv);
    oh[3] = f_to_bf16(acc.w * inv);
    *(u16x4*)(zbf + (size_t)row * 256 + lane * 4) = oh;
}

// ---------------------------------------------------------------------------
__global__ __launch_bounds__(256) void ln_kernel(
    const float* __restrict__ xin, const float* __restrict__ y,
    const float* __restrict__ g, const float* __restrict__ bsh,
    float* __restrict__ xout, unsigned short* __restrict__ xh)
{
    const int t = threadIdx.x;
    const int w = t >> 6, lane = t & 63;
    const size_t row = (size_t)blockIdx.x * 4 + w;
    const float4 xv = *(const float4*)(xin + row * 256 + lane * 4);
    const float4 yv = *(const float4*)(y + row * 256 + lane * 4);
    float4 sv;
    sv.x = xv.x + yv.x; sv.y = xv.y + yv.y; sv.z = xv.z + yv.z; sv.w = xv.w + yv.w;
    float sum = sv.x + sv.y + sv.z + sv.w;
    float sq  = sv.x * sv.x + sv.y * sv.y + sv.z * sv.z + sv.w * sv.w;
#pragma unroll
    for (int off = 1; off < 64; off <<= 1) {
        sum += __shfl_xor(sum, off, 64);
        sq  += __shfl_xor(sq, off, 64);
    }
    const float mu = sum * (1.f / 256.f);
    const float var = sq * (1.f / 256.f) - mu * mu;
    const float rs = rsqrtf(var + 1e-5f);
    const float4 gv = *(const float4*)(g + lane * 4);
    const float4 bv = *(const float4*)(bsh + lane * 4);
    float4 o;
    o.x = (sv.x - mu) * rs * gv.x + bv.x;
    o.y = (sv.y - mu) * rs * gv.y + bv.y;
    o.z = (sv.z - mu) * rs * gv.z + bv.z;
    o.w = (sv.w - mu) * rs * gv.w + bv.w;
    *(float4*)(xout + row * 256 + lane * 4) = o;
    u16x4 oh;
    oh[0] = f_to_bf16(o.x); oh[1] = f_to_bf16(o.y);
    oh[2] = f_to_bf16(o.z); oh[3] = f_to_bf16(o.w);
    *(u16x4*)(xh + row * 256 + lane * 4) = oh;
}

// ---------------------------------------------------------------------------
extern "C" void kernel_launch(void* const* d_in, const int* in_sizes, int n_in,
                              void* d_out, int out_size, void* d_ws, size_t ws_size,
                              hipStream_t stream)
{
    (void)in_sizes; (void)n_in; (void)out_size;
    const int*   tok   = (const int*)d_in[0];
    const int*   rel   = (const int*)d_in[1];
    const void*  mask  = d_in[2];
    const float* embed = (const float*)d_in[3];
    const float* W_in  = (const float*)d_in[4];
    const float* b_in  = (const float*)d_in[5];
    const float* Wq    = (const float*)d_in[6];
    const float* Wk    = (const float*)d_in[7];
    const float* Wv    = (const float*)d_in[8];
    const float* Wo    = (const float*)d_in[9];
    const float* ln1g  = (const float*)d_in[10];
    const float* ln1b  = (const float*)d_in[11];
    const float* ln2g  = (const float*)d_in[12];
    const float* ln2b  = (const float*)d_in[13];
    const float* W1    = (const float*)d_in[14];
    const float* b1    = (const float*)d_in[15];
    const float* W2    = (const float*)d_in[16];
    const float* b2    = (const float*)d_in[17];
    const float* relk  = (const float*)d_in[18];
    const float* relv  = (const float*)d_in[19];
    const float* Wout  = (const float*)d_in[20];
    const float* bout  = (const float*)d_in[21];
    float* out = (float*)d_out;
    const float scale = 0.17677669529663687f;

    float* ws = (float*)d_ws;
    float*          x     = ws;                                   // 1M f32
    unsigned short* xh    = (unsigned short*)(ws + 1048576);      // 0.5M
    unsigned short* zbf   = (unsigned short*)(ws + 1572864);      // 0.5M
    float*          zo    = ws + 2097152;                         // 1M
    unsigned short* qkvh  = (unsigned short*)(ws + 3145728);      // 1.5M
    unsigned short* hbh   = (unsigned short*)(ws + 4718592);      // 2M
    float*          zpart = ws + 6815744;                         // 2M
    float*          smpart= ws + 8912896;                         // 64K
    unsigned short* qrkg  = (unsigned short*)(ws + 8978432);      // 1.6384M
    int*            flag  = (int*)(ws + 10616832);
    unsigned short* wt    = (unsigned short*)(ws + 10616848);

    const size_t wsf = ws_size >> 2;
    const bool tierA = wsf >= 13271100;   // all-layer weight cache + dedicated rel16
    short* rel16 = tierA ? (short*)(ws + 12222480) : (short*)hbh;

    detect_mask_kernel<<<1, 256, 0, stream>>>((const unsigned char*)mask, flag);
    embed_proj_kernel<<<512, 256, 0, stream>>>(tok, embed, W_in, b_in, x, xh);
    if (tierA) {
        prep_rel16<<<4096, 256, 0, stream>>>(rel, mask, flag, rel16);
        tcast256<<<dim3(8, 8, 17), 256, 0, stream>>>(Wq, Wk, Wv, Wo, Wout, wt, 4, scale);
        tcastKN<<<dim3(32, 8, 4), 256, 0, stream>>>(W1, wt + 262144, 256, 1024, 262144, 786432);
        tcastKN<<<dim3(8, 32, 4), 256, 0, stream>>>(W2, wt + 524288, 1024, 256, 262144, 786432);
    }

    for (int l = 0; l < 4; ++l) {
        unsigned short* wl = tierA ? wt + (size_t)l * 786432 : wt;
        if (!tierA) {
            prep_rel16<<<4096, 256, 0, stream>>>(rel, mask, flag, rel16);
            tcast256<<<dim3(8, 8, 4), 256, 0, stream>>>(
                Wq + (size_t)l * 65536, Wk + (size_t)l * 65536,
                Wv + (size_t)l * 65536, Wo + (size_t)l * 65536, Wout, wt, 1, scale);
            tcastKN<<<dim3(32, 8, 1), 256, 0, stream>>>(W1 + (size_t)l * 262144, wt + 262144, 256, 1024, 0, 0);
            tcastKN<<<dim3(8, 32, 1), 256, 0, stream>>>(W2 + (size_t)l * 262144, wt + 524288, 1024, 256, 0, 0);
        }
        // fused QKV (q pre-scaled): xh @ WqkvT -> qkvh bf16
        gemm_bf16_128<<<dim3(12, 32), 256, 0, stream>>>(xh, wl, nullptr, nullptr, qkvh,
                                                        NTOK, 256, 768, 0);
        qrk_kernel<<<dim3(8, 8, 8), 256, 0, stream>>>(qkvh, relk, qrkg);
        attn_mfma<<<1024, 256, 0, stream>>>(qkvh, rel16, qrkg, relv, zpart, smpart);
        combine_kernel<<<1024, 256, 0, stream>>>(zpart, smpart, zbf);
        gemm_bf16_64<<<dim3(4, 64), 256, 0, stream>>>(zbf, wl + 196608, nullptr, zo, nullptr,
                                                      NTOK, 256, 256, 0);
        ln_kernel<<<1024, 256, 0, stream>>>(x, zo, ln1g + l * 256, ln1b + l * 256, x, xh);
        gemm_bf16_128<<<dim3(16, 32), 256, 0, stream>>>(xh, wl + 262144, b1 + l * 1024, nullptr, hbh,
                                                        NTOK, 256, 1024, 1);
        gemm_bf16_64<<<dim3(4, 64), 256, 0, stream>>>(hbh, wl + 524288, b2 + l * 256, zo, nullptr,
                                                      NTOK, 1024, 256, 0);
        ln_kernel<<<1024, 256, 0, stream>>>(x, zo, ln2g + l * 256, ln2b + l * 256, x, xh);
    }
    unsigned short* woutT = wt;
    if (tierA) {
        woutT = wt + (size_t)4 * 786432;
    } else {
        tcast256<<<dim3(8, 8, 1), 256, 0, stream>>>(Wq, Wk, Wv, Wo, Wout, wt, 0, scale);
    }
    gemm_bf16_64<<<dim3(4, 64), 256, 0, stream>>>(xh, woutT, bout, out, nullptr,
                                                  NTOK, 256, 256, 0);
}

// Round 10
// 646.615 us; speedup vs baseline: 1.0917x; 1.0002x over previous
//
#include <hip/hip_runtime.h>
#include <hip/hip_bf16.h>

#define NTOK 4096   // B*N
#define NN   512

typedef __attribute__((ext_vector_type(8))) short bf16x8;
typedef __attribute__((ext_vector_type(4))) float f32x4;
typedef __attribute__((ext_vector_type(4))) unsigned short u16x4;

__device__ __forceinline__ float bf16_to_f(unsigned short u) {
    unsigned int x = ((unsigned int)u) << 16;
    return __builtin_bit_cast(float, x);
}
__device__ __forceinline__ unsigned short f_to_bf16(float f) {
    unsigned int b = __builtin_bit_cast(unsigned int, f);
    return (unsigned short)((b + 0x7fff + ((b >> 16) & 1)) >> 16);
}
__device__ __forceinline__ bf16x8 pack8(float4 a, float4 b) {
    bf16x8 v;
    v[0]=(short)f_to_bf16(a.x); v[1]=(short)f_to_bf16(a.y);
    v[2]=(short)f_to_bf16(a.z); v[3]=(short)f_to_bf16(a.w);
    v[4]=(short)f_to_bf16(b.x); v[5]=(short)f_to_bf16(b.y);
    v[6]=(short)f_to_bf16(b.z); v[7]=(short)f_to_bf16(b.w);
    return v;
}

// ---------------------------------------------------------------------------
__global__ void detect_mask_kernel(const unsigned char* __restrict__ m, int* __restrict__ flag) {
    __shared__ int f;
    if (threadIdx.x == 0) f = 0;
    __syncthreads();
    int any = 0;
    for (int i = threadIdx.x; i < 4096; i += 256) {
        if ((i & 3) != 0 && m[i] != 0) any = 1;
    }
    if (any) atomicOr(&f, 1);
    __syncthreads();
    if (threadIdx.x == 0) *flag = f;   // 1 => byte mask, 0 => int32 mask
}

// ---------------------------------------------------------------------------
__global__ __launch_bounds__(256) void prep_rel16(
    const int* __restrict__ rel, const void* __restrict__ mask,
    const int* __restrict__ flag, short* __restrict__ rel16)
{
    const bool mbyte = (*flag != 0);
    const unsigned char* m8 = (const unsigned char*)mask;
    const int* m32 = (const int*)mask;
    const int i = (blockIdx.x * 256 + threadIdx.x) * 2;
    int2 rv = *(const int2*)(rel + i);
    int ok0, ok1;
    if (mbyte) { ok0 = m8[i]; ok1 = m8[i + 1]; }
    else       { ok0 = (m32[i] != 0); ok1 = (m32[i + 1] != 0); }
    short2 o;
    o.x = ok0 ? (short)rv.x : (short)-1;
    o.y = ok1 ? (short)rv.y : (short)-1;
    *(short2*)(rel16 + i) = o;
}

// ---------------------------------------------------------------------------
// Transpose-cast: out[n][k] = bf16(in[k][n] * sc), 256x256 weights (+Wout).
__global__ __launch_bounds__(256) void tcast256(
    const float* __restrict__ Wq, const float* __restrict__ Wk,
    const float* __restrict__ Wv, const float* __restrict__ Wo,
    const float* __restrict__ Wout, unsigned short* __restrict__ wt,
    int nL, float scale)
{
    const int z = blockIdx.z;
    const float* src; unsigned short* dst; float sc = 1.f;
    if (z >= nL * 4) {
        src = Wout; dst = wt + (size_t)nL * 786432;
    } else {
        const int l = z >> 2, which = z & 3;
        if      (which == 0) { src = Wq + (size_t)l * 65536; sc = scale; }
        else if (which == 1) { src = Wk + (size_t)l * 65536; }
        else if (which == 2) { src = Wv + (size_t)l * 65536; }
        else                 { src = Wo + (size_t)l * 65536; }
        dst = wt + (size_t)l * 786432 + which * 65536;
    }
    __shared__ float tile[32][33];
    const int t = threadIdx.x, tx = t & 31, ty = t >> 5;
    const int n0 = blockIdx.x * 32, k0 = blockIdx.y * 32;
#pragma unroll
    for (int p = 0; p < 4; ++p)
        tile[ty + p * 8][tx] = src[(size_t)(k0 + ty + p * 8) * 256 + n0 + tx];
    __syncthreads();
#pragma unroll
    for (int p = 0; p < 4; ++p)
        dst[(size_t)(n0 + ty + p * 8) * 256 + k0 + tx] = f_to_bf16(tile[tx][ty + p * 8] * sc);
}

// Generic transpose-cast for W1/W2 (z = layer index).
__global__ __launch_bounds__(256) void tcastKN(
    const float* __restrict__ in, unsigned short* __restrict__ out,
    int K, int N, long inStride, long outStride)
{
    in  += (size_t)blockIdx.z * inStride;
    out += (size_t)blockIdx.z * outStride;
    __shared__ float tile[32][33];
    const int t = threadIdx.x, tx = t & 31, ty = t >> 5;
    const int n0 = blockIdx.x * 32, k0 = blockIdx.y * 32;
#pragma unroll
    for (int p = 0; p < 4; ++p)
        tile[ty + p * 8][tx] = in[(size_t)(k0 + ty + p * 8) * N + n0 + tx];
    __syncthreads();
#pragma unroll
    for (int p = 0; p < 4; ++p)
        out[(size_t)(n0 + ty + p * 8) * K + k0 + tx] = f_to_bf16(tile[tx][ty + p * 8]);
}

// ---------------------------------------------------------------------------
__global__ __launch_bounds__(256) void embed_proj_kernel(
    const int* __restrict__ tok, const float* __restrict__ embed,
    const float* __restrict__ W_in, const float* __restrict__ b_in,
    float* __restrict__ x, unsigned short* __restrict__ xh)
{
    __shared__ float emb[8][304];
    __shared__ int tloc[8];
    const int t = threadIdx.x;
    const int r0 = blockIdx.x * 8;
    if (t < 8) tloc[t] = tok[r0 + t];
    __syncthreads();
    for (int i = t; i < 8 * 300; i += 256) {
        int r = i / 300, e = i - r * 300;
        emb[r][e] = embed[(size_t)tloc[r] * 300 + e];
    }
    __syncthreads();
    float acc[8] = {0.f,0.f,0.f,0.f,0.f,0.f,0.f,0.f};
    const int d = t;
    for (int e = 0; e < 300; ++e) {
        float w = W_in[e * 256 + d];
#pragma unroll
        for (int r = 0; r < 8; ++r) acc[r] += emb[r][e] * w;
    }
    const float bb = b_in[d];
#pragma unroll
    for (int r = 0; r < 8; ++r) {
        float o = acc[r] + bb;
        o = o > 0.f ? o : 0.f;
        x[(size_t)(r0 + r) * 256 + d] = o;
        xh[(size_t)(r0 + r) * 256 + d] = f_to_bf16(o);
    }
}

// ---------------------------------------------------------------------------
// bf16 GEMM, 64x64 tile. A bf16 [M][K], WT bf16 [Nc][K]. Out f32 (Cf) or bf16 (Ch).
__global__ __launch_bounds__(256) void gemm_bf16_64(
    const unsigned short* __restrict__ A, const unsigned short* __restrict__ WT,
    const float* __restrict__ bias, float* __restrict__ Cf, unsigned short* __restrict__ Ch,
    int M, int K, int Nc, int relu)
{
    __shared__ unsigned short As[2][64][40];
    __shared__ unsigned short Bs[2][64][40];
    const int t = threadIdx.x;
    const int lane = t & 63, w = t >> 6;
    const int g = lane >> 4, li = lane & 15;
    const int r0 = blockIdx.y * 64, c0 = blockIdx.x * 64;

    f32x4 acc[4];
#pragma unroll
    for (int i = 0; i < 4; ++i) acc[i] = (f32x4){0.f,0.f,0.f,0.f};

    const int arow = t >> 2, ad8 = (t & 3) * 8;

    bf16x8 a0 = *(const bf16x8*)(A  + (size_t)(r0 + arow) * K + ad8);
    bf16x8 b0 = *(const bf16x8*)(WT + (size_t)(c0 + arow) * K + ad8);

    const int nk = K >> 5;
    for (int ki = 0; ki < nk; ++ki) {
        const int cur = ki & 1;
        *(bf16x8*)&As[cur][arow][ad8] = a0;
        *(bf16x8*)&Bs[cur][arow][ad8] = b0;
        if (ki + 1 < nk) {
            const int k0 = (ki + 1) * 32;
            a0 = *(const bf16x8*)(A  + (size_t)(r0 + arow) * K + k0 + ad8);
            b0 = *(const bf16x8*)(WT + (size_t)(c0 + arow) * K + k0 + ad8);
        }
        __syncthreads();
        bf16x8 af = *(const bf16x8*)&As[cur][16 * w + li][g * 8];
#pragma unroll
        for (int sub = 0; sub < 4; ++sub) {
            bf16x8 bfr = *(const bf16x8*)&Bs[cur][16 * sub + li][g * 8];
            acc[sub] = __builtin_amdgcn_mfma_f32_16x16x32_bf16(af, bfr, acc[sub], 0, 0, 0);
        }
    }
#pragma unroll
    for (int sub = 0; sub < 4; ++sub) {
        int col = c0 + sub * 16 + li;
        float bv = bias ? bias[col] : 0.f;
#pragma unroll
        for (int r = 0; r < 4; ++r) {
            int row = r0 + 16 * w + g * 4 + r;
            float o = acc[sub][r] + bv;
            if (relu) o = fmaxf(o, 0.f);
            if (Ch) Ch[(size_t)row * Nc + col] = f_to_bf16(o);
            else    Cf[(size_t)row * Nc + col] = o;
        }
    }
}

// ---------------------------------------------------------------------------
// bf16 GEMM, 128x64 tile (QKV, FFN1).
__global__ __launch_bounds__(256) void gemm_bf16_128(
    const unsigned short* __restrict__ A, const unsigned short* __restrict__ WT,
    const float* __restrict__ bias, float* __restrict__ Cf, unsigned short* __restrict__ Ch,
    int M, int K, int Nc, int relu)
{
    __shared__ unsigned short As[2][128][40];
    __shared__ unsigned short Bs[2][64][40];
    const int t = threadIdx.x;
    const int lane = t & 63, w = t >> 6;
    const int g = lane >> 4, li = lane & 15;
    const int r0 = blockIdx.y * 128, c0 = blockIdx.x * 64;

    f32x4 acc[2][4];
#pragma unroll
    for (int i = 0; i < 2; ++i)
#pragma unroll
        for (int j = 0; j < 4; ++j) acc[i][j] = (f32x4){0.f,0.f,0.f,0.f};

    const int arow = t >> 1, ah = (t & 1) * 16;
    const int bcol = t >> 2, bk8 = (t & 3) * 8;

    bf16x8 a0 = *(const bf16x8*)(A + (size_t)(r0 + arow) * K + ah);
    bf16x8 a1 = *(const bf16x8*)(A + (size_t)(r0 + arow) * K + ah + 8);
    bf16x8 b0 = *(const bf16x8*)(WT + (size_t)(c0 + bcol) * K + bk8);

    const int nk = K >> 5;
    for (int ki = 0; ki < nk; ++ki) {
        const int cur = ki & 1;
        *(bf16x8*)&As[cur][arow][ah]     = a0;
        *(bf16x8*)&As[cur][arow][ah + 8] = a1;
        *(bf16x8*)&Bs[cur][bcol][bk8]    = b0;
        if (ki + 1 < nk) {
            const int k0 = (ki + 1) * 32;
            a0 = *(const bf16x8*)(A + (size_t)(r0 + arow) * K + k0 + ah);
            a1 = *(const bf16x8*)(A + (size_t)(r0 + arow) * K + k0 + ah + 8);
            b0 = *(const bf16x8*)(WT + (size_t)(c0 + bcol) * K + k0 + bk8);
        }
        __syncthreads();
        bf16x8 af0 = *(const bf16x8*)&As[cur][32 * w + li][g * 8];
        bf16x8 af1 = *(const bf16x8*)&As[cur][32 * w + 16 + li][g * 8];
#pragma unroll
        for (int sub = 0; sub < 4; ++sub) {
            bf16x8 bfr = *(const bf16x8*)&Bs[cur][16 * sub + li][g * 8];
            acc[0][sub] = __builtin_amdgcn_mfma_f32_16x16x32_bf16(af0, bfr, acc[0][sub], 0, 0, 0);
            acc[1][sub] = __builtin_amdgcn_mfma_f32_16x16x32_bf16(af1, bfr, acc[1][sub], 0, 0, 0);
        }
    }
#pragma unroll
    for (int rc = 0; rc < 2; ++rc)
#pragma unroll
    for (int sub = 0; sub < 4; ++sub) {
        int col = c0 + sub * 16 + li;
        float bv = bias ? bias[col] : 0.f;
#pragma unroll
        for (int r = 0; r < 4; ++r) {
            int row = r0 + 32 * w + rc * 16 + g * 4 + r;
            float o = acc[rc][sub][r] + bv;
            if (relu) o = fmaxf(o, 0.f);
            if (Ch) Ch[(size_t)row * Nc + col] = f_to_bf16(o);
            else    Cf[(size_t)row * Nc + col] = o;
        }
    }
}

// ---------------------------------------------------------------------------
// qrk[b,h,n,rel] = q_n . relk[rel]  (q pre-scaled in Wq cast). Block=(chunk,h,b).
__global__ __launch_bounds__(256) void qrk_kernel(
    const unsigned short* __restrict__ qkvh, const float* __restrict__ relk_g,
    unsigned short* __restrict__ qrkg)
{
    const int n0 = blockIdx.x * 64, h = blockIdx.y, b = blockIdx.z;
    const int t = threadIdx.x, lane = t & 63, w = t >> 6;
    const int g = lane >> 4, li = lane & 15;
    const int qrow = 16 * w + g * 4;

    __shared__ unsigned short relk_s[100][40];
    for (int i = t; i < 400; i += 256) {
        int rr = i >> 2, d8 = (i & 3) * 8;
        const float* sp = relk_g + rr * 32 + d8;
        *(bf16x8*)&relk_s[rr][d8] = pack8(*(const float4*)sp, *(const float4*)(sp + 4));
    }
    bf16x8 qf = *(const bf16x8*)(qkvh + (size_t)(b * NN + n0 + 16 * w + li) * 768 + h * 32 + g * 8);
    __syncthreads();
#pragma unroll
    for (int rc = 0; rc < 7; ++rc) {
        bf16x8 bb = *(const bf16x8*)&relk_s[rc * 16 + li][g * 8];
        f32x4 s = __builtin_amdgcn_mfma_f32_16x16x32_bf16(qf, bb, (f32x4){0.f,0.f,0.f,0.f}, 0, 0, 0);
        int col = rc * 16 + li;
        if (col < 100) {
#pragma unroll
            for (int r = 0; r < 4; ++r)
                qrkg[((size_t)(b * 8 + h) * NN + n0 + qrow + r) * 100 + col] = f_to_bf16(s[r]);
        }
    }
}

// ---------------------------------------------------------------------------
// Attention, BARRIER-FREE main loop: wrel/qrk rows are wave-partitioned, V
// fragments load per-wave straight from L2, p_s is per-wave. Waves drift to
// hide each other's latency. Only 2 barriers (around shared relvT epilogue).
__global__ __launch_bounds__(256) void attn_mfma(
    const unsigned short* __restrict__ qkvh,  // [4096][768] bf16, q pre-scaled
    const short* __restrict__ rel16,
    const unsigned short* __restrict__ qrkg,  // [64][512][100] bf16
    const float* __restrict__ relv_g,
    float* __restrict__ zpart, float* __restrict__ smpart)
{
    const int p = blockIdx.x;            // 0..1023
    const int cx = p & 7, idx0 = p >> 3;
    const int sg = cx * 8 + (idx0 >> 4); // (b,chunk) slice, XCD-grouped
    const int hm = idx0 & 15;
    const int h = hm >> 1, ms = hm & 1;
    const int b = sg >> 3, chunk = sg & 7;
    const int n0 = chunk * 64, mbase = ms * 256;

    const int t = threadIdx.x;
    const int lane = t & 63, w = t >> 6;
    const int g = lane >> 4, li = lane & 15;
    const int qrow = 16 * w + g * 4;

    __shared__ float wrel[64][100];            // 25600 B (wave-partitioned rows)
    __shared__ unsigned short qrk_lds[64][100];// 12800 B (wave-partitioned rows)
    __shared__ union {
        unsigned short relvT[32][136];         // 8704 B (epilogue, shared)
        unsigned short p_s[4][16][40];         // 5120 B (per-wave)
    } u;                                       // 47104 B total -> 3 blocks/CU

    // ---- per-wave prologue (NO barrier): zero own wrel rows, stage own qrk rows
    for (int i = lane; i < 1600; i += 64) {
        int row = i / 100;
        wrel[16 * w + row][i - row * 100] = 0.f;
    }
    {
        const unsigned short* qsrc = qrkg + ((size_t)(b * 8 + h) * NN + n0 + 16 * w) * 100;
        for (int i = lane; i < 800; i += 64) {
            int row = i / 50, off = (i - row * 50) * 2;
            *(unsigned int*)&qrk_lds[16 * w + row][off] =
                *(const unsigned int*)(qsrc + (size_t)row * 100 + off);
        }
    }
    bf16x8 qf = *(const bf16x8*)(qkvh + (size_t)(b * NN + n0 + 16 * w + li) * 768 + h * 32 + g * 8);

    const short* relrow[4];
#pragma unroll
    for (int r = 0; r < 4; ++r)
        relrow[r] = rel16 + ((size_t)b * NN + n0 + qrow + r) * NN;
    const size_t kRB  = (size_t)(b * NN) * 768 + 256 + h * 32 + g * 8;
    const size_t vRB2 = (size_t)(b * NN) * 768 + 512 + h * 32;

    bf16x8 kbuf[2][2]; bf16x8 vb[2][2]; short rbuf[2][8];
    {   // tile-0 prefetch
#pragma unroll
        for (int i = 0; i < 8; ++i)
            rbuf[0][i] = relrow[i & 3][mbase + (i >> 2) * 16 + li];
        kbuf[0][0] = *(const bf16x8*)(qkvh + kRB + (size_t)(mbase + li) * 768);
        kbuf[0][1] = *(const bf16x8*)(qkvh + kRB + (size_t)(mbase + 16 + li) * 768);
#pragma unroll
        for (int dc = 0; dc < 2; ++dc) {
            bf16x8 v;
#pragma unroll
            for (int j = 0; j < 8; ++j)
                v[j] = (short)qkvh[vRB2 + (size_t)(mbase + g * 8 + j) * 768 + dc * 16 + li];
            vb[0][dc] = v;
        }
    }

    float smacc[4] = {0.f, 0.f, 0.f, 0.f};
    f32x4 zf[2];
    zf[0] = (f32x4){0.f,0.f,0.f,0.f};
    zf[1] = (f32x4){0.f,0.f,0.f,0.f};

    // ---- main loop: 8 tiles of 32 m, NO __syncthreads
#pragma unroll
    for (int tt = 0; tt < 8; ++tt) {
        const int cur = tt & 1, nxt = cur ^ 1;
        if (tt + 1 < 8) {   // issue next tile's loads first (hide under compute)
            const int m0n = mbase + (tt + 1) * 32;
#pragma unroll
            for (int i = 0; i < 8; ++i)
                rbuf[nxt][i] = relrow[i & 3][m0n + (i >> 2) * 16 + li];
            kbuf[nxt][0] = *(const bf16x8*)(qkvh + kRB + (size_t)(m0n + li) * 768);
            kbuf[nxt][1] = *(const bf16x8*)(qkvh + kRB + (size_t)(m0n + 16 + li) * 768);
#pragma unroll
            for (int dc = 0; dc < 2; ++dc) {
                bf16x8 v;
#pragma unroll
                for (int j = 0; j < 8; ++j)
                    v[j] = (short)qkvh[vRB2 + (size_t)(m0n + g * 8 + j) * 768 + dc * 16 + li];
                vb[nxt][dc] = v;
            }
        }
        // QK^T
        f32x4 s0 = __builtin_amdgcn_mfma_f32_16x16x32_bf16(qf, kbuf[cur][0], (f32x4){0.f,0.f,0.f,0.f}, 0, 0, 0);
        f32x4 s1 = __builtin_amdgcn_mfma_f32_16x16x32_bf16(qf, kbuf[cur][1], (f32x4){0.f,0.f,0.f,0.f}, 0, 0, 0);
        // scores -> p; wrel scatter (own-wave rows); p_s store (own-wave)
        float pr[8];
#pragma unroll
        for (int i = 0; i < 8; ++i) {
            const int r = i & 3;
            const int rl = rbuf[cur][i];
            const float qadd = bf16_to_f(qrk_lds[qrow + r][rl < 0 ? 0 : rl]);
            const float sv = ((i >> 2) ? s1[r] : s0[r]) + qadd;
            float pv = 0.f;
            if (rl >= 0) {
                pv = __expf(fminf(sv, 50.f));
                atomicAdd(&wrel[qrow + r][rl], pv);
            }
            smacc[r] += pv;
            pr[i] = pv;
        }
#pragma unroll
        for (int i = 0; i < 8; ++i)
            u.p_s[w][g * 4 + (i & 3)][(i >> 2) * 16 + li] = f_to_bf16(pr[i]);
        asm volatile("s_waitcnt lgkmcnt(0)" ::: "memory");
        __builtin_amdgcn_sched_barrier(0);
        // PV from per-wave register V-frags
        bf16x8 pa = *(const bf16x8*)&u.p_s[w][li][g * 8];
        zf[0] = __builtin_amdgcn_mfma_f32_16x16x32_bf16(pa, vb[cur][0], zf[0], 0, 0, 0);
        zf[1] = __builtin_amdgcn_mfma_f32_16x16x32_bf16(pa, vb[cur][1], zf[1], 0, 0, 0);
    }
    __syncthreads();   // all waves done with p_s before relvT overwrites union

    // epilogue: stage relv^T (shared), add wrel @ relv, write partials
    for (int i = t; i < 32 * 36; i += 256) {
        int d = i / 36, c = 100 + (i - (i / 36) * 36);
        u.relvT[d][c] = 0;
    }
    for (int i = t; i < 400; i += 256) {
        int rr2 = i >> 2, d8 = (i & 3) * 8;
        const float* sp = relv_g + rr2 * 32 + d8;
        float4 s0 = *(const float4*)sp, s1 = *(const float4*)(sp + 4);
        u.relvT[d8 + 0][rr2] = f_to_bf16(s0.x);
        u.relvT[d8 + 1][rr2] = f_to_bf16(s0.y);
        u.relvT[d8 + 2][rr2] = f_to_bf16(s0.z);
        u.relvT[d8 + 3][rr2] = f_to_bf16(s0.w);
        u.relvT[d8 + 4][rr2] = f_to_bf16(s1.x);
        u.relvT[d8 + 5][rr2] = f_to_bf16(s1.y);
        u.relvT[d8 + 6][rr2] = f_to_bf16(s1.z);
        u.relvT[d8 + 7][rr2] = f_to_bf16(s1.w);
    }
    __syncthreads();
#pragma unroll
    for (int kc = 0; kc < 4; ++kc) {
        const int kbase = kc * 32 + g * 8;
        const float* wp = &wrel[16 * w + li][0];
        bf16x8 af;
#pragma unroll
        for (int j = 0; j < 8; ++j) {
            int id = kbase + j;
            float val = (id < 100) ? wp[id] : 0.f;
            af[j] = (short)f_to_bf16(val);
        }
#pragma unroll
        for (int dc = 0; dc < 2; ++dc) {
            bf16x8 vbr = *(const bf16x8*)&u.relvT[dc * 16 + li][kbase];
            zf[dc] = __builtin_amdgcn_mfma_f32_16x16x32_bf16(af, vbr, zf[dc], 0, 0, 0);
        }
    }
#pragma unroll
    for (int r = 0; r < 4; ++r) {
        smacc[r] += __shfl_xor(smacc[r], 1, 64);
        smacc[r] += __shfl_xor(smacc[r], 2, 64);
        smacc[r] += __shfl_xor(smacc[r], 4, 64);
        smacc[r] += __shfl_xor(smacc[r], 8, 64);
    }
#pragma unroll
    for (int r = 0; r < 4; ++r) {
        const int row = b * NN + n0 + qrow + r;
        size_t ob = (size_t)ms * 1048576 + (size_t)row * 256 + h * 32;
#pragma unroll
        for (int dc = 0; dc < 2; ++dc)
            zpart[ob + dc * 16 + li] = zf[dc][r];
        if (li == 0)
            smpart[(size_t)ms * 32768 + (size_t)row * 8 + h] = smacc[r];
    }
}

// ---------------------------------------------------------------------------
__global__ __launch_bounds__(256) void combine_kernel(
    const float* __restrict__ zpart, const float* __restrict__ smpart,
    unsigned short* __restrict__ zbf)
{
    const int t = threadIdx.x;
    const int wi = t >> 6, lane = t & 63;
    const int row = blockIdx.x * 4 + wi;
    const int h = lane >> 3;
    float den = 0.f;
    float4 acc = make_float4(0.f, 0.f, 0.f, 0.f);
#pragma unroll
    for (int s = 0; s < 2; ++s) {
        den += smpart[(size_t)s * 32768 + (size_t)row * 8 + h];
        float4 v = *(const float4*)(zpart + (size_t)s * 1048576 + (size_t)row * 256 + lane * 4);
        acc.x += v.x; acc.y += v.y; acc.z += v.z; acc.w += v.w;
    }
    const float inv = 1.f / den;
    u16x4 oh;
    oh[0] = f_to_bf16(acc.x * inv);
    oh[1] = f_to_bf16(acc.y * inv);
    oh[2] = f_to_bf16(acc.z * inv);
    oh[3] = f_to_bf16(acc.w * inv);
    *(u16x4*)(zbf + (size_t)row * 256 + lane * 4) = oh;
}

// ---------------------------------------------------------------------------
__global__ __launch_bounds__(256) void ln_kernel(
    const float* __restrict__ xin, const float* __restrict__ y,
    const float* __restrict__ g, const float* __restrict__ bsh,
    float* __restrict__ xout, unsigned short* __restrict__ xh)
{
    const int t = threadIdx.x;
    const int w = t >> 6, lane = t & 63;
    const size_t row = (size_t)blockIdx.x * 4 + w;
    const float4 xv = *(const float4*)(xin + row * 256 + lane * 4);
    const float4 yv = *(const float4*)(y + row * 256 + lane * 4);
    float4 sv;
    sv.x = xv.x + yv.x; sv.y = xv.y + yv.y; sv.z = xv.z + yv.z; sv.w = xv.w + yv.w;
    float sum = sv.x + sv.y + sv.z + sv.w;
    float sq  = sv.x * sv.x + sv.y * sv.y + sv.z * sv.z + sv.w * sv.w;
#pragma unroll
    for (int off = 1; off < 64; off <<= 1) {
        sum += __shfl_xor(sum, off, 64);
        sq  += __shfl_xor(sq, off, 64);
    }
    const float mu = sum * (1.f / 256.f);
    const float var = sq * (1.f / 256.f) - mu * mu;
    const float rs = rsqrtf(var + 1e-5f);
    const float4 gv = *(const float4*)(g + lane * 4);
    const float4 bv = *(const float4*)(bsh + lane * 4);
    float4 o;
    o.x = (sv.x - mu) * rs * gv.x + bv.x;
    o.y = (sv.y - mu) * rs * gv.y + bv.y;
    o.z = (sv.z - mu) * rs * gv.z + bv.z;
    o.w = (sv.w - mu) * rs * gv.w + bv.w;
    *(float4*)(xout + row * 256 + lane * 4) = o;
    u16x4 oh;
    oh[0] = f_to_bf16(o.x); oh[1] = f_to_bf16(o.y);
    oh[2] = f_to_bf16(o.z); oh[3] = f_to_bf16(o.w);
    *(u16x4*)(xh + row * 256 + lane * 4) = oh;
}

// ---------------------------------------------------------------------------
extern "C" void kernel_launch(void* const* d_in, const int* in_sizes, int n_in,
                              void* d_out, int out_size, void* d_ws, size_t ws_size,
                              hipStream_t stream)
{
    (void)in_sizes; (void)n_in; (void)out_size;
    const int*   tok   = (const int*)d_in[0];
    const int*   rel   = (const int*)d_in[1];
    const void*  mask  = d_in[2];
    const float* embed = (const float*)d_in[3];
    const float* W_in  = (const float*)d_in[4];
    const float* b_in  = (const float*)d_in[5];
    const float* Wq    = (const float*)d_in[6];
    const float* Wk    = (const float*)d_in[7];
    const float* Wv    = (const float*)d_in[8];
    const float* Wo    = (const float*)d_in[9];
    const float* ln1g  = (const float*)d_in[10];
    const float* ln1b  = (const float*)d_in[11];
    const float* ln2g  = (const float*)d_in[12];
    const float* ln2b  = (const float*)d_in[13];
    const float* W1    = (const float*)d_in[14];
    const float* b1    = (const float*)d_in[15];
    const float* W2    = (const float*)d_in[16];
    const float* b2    = (const float*)d_in[17];
    const float* relk  = (const float*)d_in[18];
    const float* relv  = (const float*)d_in[19];
    const float* Wout  = (const float*)d_in[20];
    const float* bout  = (const float*)d_in[21];
    float* out = (float*)d_out;
    const float scale = 0.17677669529663687f;

    float* ws = (float*)d_ws;
    float*          x     = ws;                                   // 1M f32
    unsigned short* xh    = (unsigned short*)(ws + 1048576);      // 0.5M
    unsigned short* zbf   = (unsigned short*)(ws + 1572864);      // 0.5M
    float*          zo    = ws + 2097152;                         // 1M
    unsigned short* qkvh  = (unsigned short*)(ws + 3145728);      // 1.5M
    unsigned short* hbh   = (unsigned short*)(ws + 4718592);      // 2M
    float*          zpart = ws + 6815744;                         // 2M
    float*          smpart= ws + 8912896;                         // 64K
    unsigned short* qrkg  = (unsigned short*)(ws + 8978432);      // 1.6384M
    int*            flag  = (int*)(ws + 10616832);
    unsigned short* wt    = (unsigned short*)(ws + 10616848);

    const size_t wsf = ws_size >> 2;
    const bool tierA = wsf >= 13271100;   // all-layer weight cache + dedicated rel16
    short* rel16 = tierA ? (short*)(ws + 12222480) : (short*)hbh;

    detect_mask_kernel<<<1, 256, 0, stream>>>((const unsigned char*)mask, flag);
    embed_proj_kernel<<<512, 256, 0, stream>>>(tok, embed, W_in, b_in, x, xh);
    if (tierA) {
        prep_rel16<<<4096, 256, 0, stream>>>(rel, mask, flag, rel16);
        tcast256<<<dim3(8, 8, 17), 256, 0, stream>>>(Wq, Wk, Wv, Wo, Wout, wt, 4, scale);
        tcastKN<<<dim3(32, 8, 4), 256, 0, stream>>>(W1, wt + 262144, 256, 1024, 262144, 786432);
        tcastKN<<<dim3(8, 32, 4), 256, 0, stream>>>(W2, wt + 524288, 1024, 256, 262144, 786432);
    }

    for (int l = 0; l < 4; ++l) {
        unsigned short* wl = tierA ? wt + (size_t)l * 786432 : wt;
        if (!tierA) {
            prep_rel16<<<4096, 256, 0, stream>>>(rel, mask, flag, rel16);
            tcast256<<<dim3(8, 8, 4), 256, 0, stream>>>(
                Wq + (size_t)l * 65536, Wk + (size_t)l * 65536,
                Wv + (size_t)l * 65536, Wo + (size_t)l * 65536, Wout, wt, 1, scale);
            tcastKN<<<dim3(32, 8, 1), 256, 0, stream>>>(W1 + (size_t)l * 262144, wt + 262144, 256, 1024, 0, 0);
            tcastKN<<<dim3(8, 32, 1), 256, 0, stream>>>(W2 + (size_t)l * 262144, wt + 524288, 1024, 256, 0, 0);
        }
        // fused QKV (q pre-scaled): xh @ WqkvT -> qkvh bf16
        gemm_bf16_128<<<dim3(12, 32), 256, 0, stream>>>(xh, wl, nullptr, nullptr, qkvh,
                                                        NTOK, 256, 768, 0);
        qrk_kernel<<<dim3(8, 8, 8), 256, 0, stream>>>(qkvh, relk, qrkg);
        attn_mfma<<<1024, 256, 0, stream>>>(qkvh, rel16, qrkg, relv, zpart, smpart);
        combine_kernel<<<1024, 256, 0, stream>>>(zpart, smpart, zbf);
        gemm_bf16_64<<<dim3(4, 64), 256, 0, stream>>>(zbf, wl + 196608, nullptr, zo, nullptr,
                                                      NTOK, 256, 256, 0);
        ln_kernel<<<1024, 256, 0, stream>>>(x, zo, ln1g + l * 256, ln1b + l * 256, x, xh);
        gemm_bf16_128<<<dim3(16, 32), 256, 0, stream>>>(xh, wl + 262144, b1 + l * 1024, nullptr, hbh,
                                                        NTOK, 256, 1024, 1);
        gemm_bf16_64<<<dim3(4, 64), 256, 0, stream>>>(hbh, wl + 524288, b2 + l * 256, zo, nullptr,
                                                      NTOK, 1024, 256, 0);
        ln_kernel<<<1024, 256, 0, stream>>>(x, zo, ln2g + l * 256, ln2b + l * 256, x, xh);
    }
    unsigned short* woutT = wt;
    if (tierA) {
        woutT = wt + (size_t)4 * 786432;
    } else {
        tcast256<<<dim3(8, 8, 1), 256, 0, stream>>>(Wq, Wk, Wv, Wo, Wout, wt, 0, scale);
    }
    gemm_bf16_64<<<dim3(4, 64), 256, 0, stream>>>(xh, woutT, bout, out, nullptr,
                                                  NTOK, 256, 256, 0);
}

// Round 11
// 617.303 us; speedup vs baseline: 1.1435x; 1.0475x over previous
//
#include <hip/hip_runtime.h>
#include <hip/hip_bf16.h>

#define NTOK 4096   // B*N
#define NN   512

typedef __attribute__((ext_vector_type(8))) short bf16x8;
typedef __attribute__((ext_vector_type(4))) float f32x4;
typedef __attribute__((ext_vector_type(4))) unsigned short u16x4;

__device__ __forceinline__ float bf16_to_f(unsigned short u) {
    unsigned int x = ((unsigned int)u) << 16;
    return __builtin_bit_cast(float, x);
}
__device__ __forceinline__ unsigned short f_to_bf16(float f) {
    unsigned int b = __builtin_bit_cast(unsigned int, f);
    return (unsigned short)((b + 0x7fff + ((b >> 16) & 1)) >> 16);
}
__device__ __forceinline__ bf16x8 pack8(float4 a, float4 b) {
    bf16x8 v;
    v[0]=(short)f_to_bf16(a.x); v[1]=(short)f_to_bf16(a.y);
    v[2]=(short)f_to_bf16(a.z); v[3]=(short)f_to_bf16(a.w);
    v[4]=(short)f_to_bf16(b.x); v[5]=(short)f_to_bf16(b.y);
    v[6]=(short)f_to_bf16(b.z); v[7]=(short)f_to_bf16(b.w);
    return v;
}

// ---------------------------------------------------------------------------
__global__ void detect_mask_kernel(const unsigned char* __restrict__ m, int* __restrict__ flag) {
    __shared__ int f;
    if (threadIdx.x == 0) f = 0;
    __syncthreads();
    int any = 0;
    for (int i = threadIdx.x; i < 4096; i += 256) {
        if ((i & 3) != 0 && m[i] != 0) any = 1;
    }
    if (any) atomicOr(&f, 1);
    __syncthreads();
    if (threadIdx.x == 0) *flag = f;   // 1 => byte mask, 0 => int32 mask
}

// ---------------------------------------------------------------------------
__global__ __launch_bounds__(256) void prep_rel16(
    const int* __restrict__ rel, const void* __restrict__ mask,
    const int* __restrict__ flag, short* __restrict__ rel16)
{
    const bool mbyte = (*flag != 0);
    const unsigned char* m8 = (const unsigned char*)mask;
    const int* m32 = (const int*)mask;
    const int i = (blockIdx.x * 256 + threadIdx.x) * 2;
    int2 rv = *(const int2*)(rel + i);
    int ok0, ok1;
    if (mbyte) { ok0 = m8[i]; ok1 = m8[i + 1]; }
    else       { ok0 = (m32[i] != 0); ok1 = (m32[i + 1] != 0); }
    short2 o;
    o.x = ok0 ? (short)rv.x : (short)-1;
    o.y = ok1 ? (short)rv.y : (short)-1;
    *(short2*)(rel16 + i) = o;
}

// ---------------------------------------------------------------------------
// Transpose-cast: out[n][k] = bf16(in[k][n] * sc), 256x256 weights (+Wout).
__global__ __launch_bounds__(256) void tcast256(
    const float* __restrict__ Wq, const float* __restrict__ Wk,
    const float* __restrict__ Wv, const float* __restrict__ Wo,
    const float* __restrict__ Wout, unsigned short* __restrict__ wt,
    int nL, float scale)
{
    const int z = blockIdx.z;
    const float* src; unsigned short* dst; float sc = 1.f;
    if (z >= nL * 4) {
        src = Wout; dst = wt + (size_t)nL * 786432;
    } else {
        const int l = z >> 2, which = z & 3;
        if      (which == 0) { src = Wq + (size_t)l * 65536; sc = scale; }
        else if (which == 1) { src = Wk + (size_t)l * 65536; }
        else if (which == 2) { src = Wv + (size_t)l * 65536; }
        else                 { src = Wo + (size_t)l * 65536; }
        dst = wt + (size_t)l * 786432 + which * 65536;
    }
    __shared__ float tile[32][33];
    const int t = threadIdx.x, tx = t & 31, ty = t >> 5;
    const int n0 = blockIdx.x * 32, k0 = blockIdx.y * 32;
#pragma unroll
    for (int p = 0; p < 4; ++p)
        tile[ty + p * 8][tx] = src[(size_t)(k0 + ty + p * 8) * 256 + n0 + tx];
    __syncthreads();
#pragma unroll
    for (int p = 0; p < 4; ++p)
        dst[(size_t)(n0 + ty + p * 8) * 256 + k0 + tx] = f_to_bf16(tile[tx][ty + p * 8] * sc);
}

// Generic transpose-cast for W1/W2 (z = layer index).
__global__ __launch_bounds__(256) void tcastKN(
    const float* __restrict__ in, unsigned short* __restrict__ out,
    int K, int N, long inStride, long outStride)
{
    in  += (size_t)blockIdx.z * inStride;
    out += (size_t)blockIdx.z * outStride;
    __shared__ float tile[32][33];
    const int t = threadIdx.x, tx = t & 31, ty = t >> 5;
    const int n0 = blockIdx.x * 32, k0 = blockIdx.y * 32;
#pragma unroll
    for (int p = 0; p < 4; ++p)
        tile[ty + p * 8][tx] = in[(size_t)(k0 + ty + p * 8) * N + n0 + tx];
    __syncthreads();
#pragma unroll
    for (int p = 0; p < 4; ++p)
        out[(size_t)(n0 + ty + p * 8) * K + k0 + tx] = f_to_bf16(tile[tx][ty + p * 8]);
}

// ---------------------------------------------------------------------------
__global__ __launch_bounds__(256) void embed_proj_kernel(
    const int* __restrict__ tok, const float* __restrict__ embed,
    const float* __restrict__ W_in, const float* __restrict__ b_in,
    float* __restrict__ x, unsigned short* __restrict__ xh)
{
    __shared__ float emb[8][304];
    __shared__ int tloc[8];
    const int t = threadIdx.x;
    const int r0 = blockIdx.x * 8;
    if (t < 8) tloc[t] = tok[r0 + t];
    __syncthreads();
    for (int i = t; i < 8 * 300; i += 256) {
        int r = i / 300, e = i - r * 300;
        emb[r][e] = embed[(size_t)tloc[r] * 300 + e];
    }
    __syncthreads();
    float acc[8] = {0.f,0.f,0.f,0.f,0.f,0.f,0.f,0.f};
    const int d = t;
    for (int e = 0; e < 300; ++e) {
        float w = W_in[e * 256 + d];
#pragma unroll
        for (int r = 0; r < 8; ++r) acc[r] += emb[r][e] * w;
    }
    const float bb = b_in[d];
#pragma unroll
    for (int r = 0; r < 8; ++r) {
        float o = acc[r] + bb;
        o = o > 0.f ? o : 0.f;
        x[(size_t)(r0 + r) * 256 + d] = o;
        xh[(size_t)(r0 + r) * 256 + d] = f_to_bf16(o);
    }
}

// ---------------------------------------------------------------------------
// bf16 GEMM, 64x64 tile. A bf16 [M][K], WT bf16 [Nc][K]. Out f32 (Cf) or bf16 (Ch).
__global__ __launch_bounds__(256) void gemm_bf16_64(
    const unsigned short* __restrict__ A, const unsigned short* __restrict__ WT,
    const float* __restrict__ bias, float* __restrict__ Cf, unsigned short* __restrict__ Ch,
    int M, int K, int Nc, int relu)
{
    __shared__ unsigned short As[2][64][40];
    __shared__ unsigned short Bs[2][64][40];
    const int t = threadIdx.x;
    const int lane = t & 63, w = t >> 6;
    const int g = lane >> 4, li = lane & 15;
    const int r0 = blockIdx.y * 64, c0 = blockIdx.x * 64;

    f32x4 acc[4];
#pragma unroll
    for (int i = 0; i < 4; ++i) acc[i] = (f32x4){0.f,0.f,0.f,0.f};

    const int arow = t >> 2, ad8 = (t & 3) * 8;

    bf16x8 a0 = *(const bf16x8*)(A  + (size_t)(r0 + arow) * K + ad8);
    bf16x8 b0 = *(const bf16x8*)(WT + (size_t)(c0 + arow) * K + ad8);

    const int nk = K >> 5;
    for (int ki = 0; ki < nk; ++ki) {
        const int cur = ki & 1;
        *(bf16x8*)&As[cur][arow][ad8] = a0;
        *(bf16x8*)&Bs[cur][arow][ad8] = b0;
        if (ki + 1 < nk) {
            const int k0 = (ki + 1) * 32;
            a0 = *(const bf16x8*)(A  + (size_t)(r0 + arow) * K + k0 + ad8);
            b0 = *(const bf16x8*)(WT + (size_t)(c0 + arow) * K + k0 + ad8);
        }
        __syncthreads();
        bf16x8 af = *(const bf16x8*)&As[cur][16 * w + li][g * 8];
#pragma unroll
        for (int sub = 0; sub < 4; ++sub) {
            bf16x8 bfr = *(const bf16x8*)&Bs[cur][16 * sub + li][g * 8];
            acc[sub] = __builtin_amdgcn_mfma_f32_16x16x32_bf16(af, bfr, acc[sub], 0, 0, 0);
        }
    }
#pragma unroll
    for (int sub = 0; sub < 4; ++sub) {
        int col = c0 + sub * 16 + li;
        float bv = bias ? bias[col] : 0.f;
#pragma unroll
        for (int r = 0; r < 4; ++r) {
            int row = r0 + 16 * w + g * 4 + r;
            float o = acc[sub][r] + bv;
            if (relu) o = fmaxf(o, 0.f);
            if (Ch) Ch[(size_t)row * Nc + col] = f_to_bf16(o);
            else    Cf[(size_t)row * Nc + col] = o;
        }
    }
}

// ---------------------------------------------------------------------------
// bf16 GEMM, 32x64 tile (N=256 GEMMs): doubles grid for occupancy.
// wave w: rows 16*(w&1), cols (w>>1)*32 + sub*16.
__global__ __launch_bounds__(256) void gemm_bf16_32(
    const unsigned short* __restrict__ A, const unsigned short* __restrict__ WT,
    const float* __restrict__ bias, float* __restrict__ Cf, unsigned short* __restrict__ Ch,
    int M, int K, int Nc, int relu)
{
    __shared__ unsigned short As[2][32][40];
    __shared__ unsigned short Bs[2][64][40];
    const int t = threadIdx.x;
    const int lane = t & 63, w = t >> 6;
    const int g = lane >> 4, li = lane & 15;
    const int r0 = blockIdx.y * 32, c0 = blockIdx.x * 64;

    f32x4 acc[2];
    acc[0] = (f32x4){0.f,0.f,0.f,0.f};
    acc[1] = (f32x4){0.f,0.f,0.f,0.f};

    const int arow = t >> 3, a4 = (t & 7) * 4;     // 32 rows x 8 thr x 4 k
    const int bcol = t >> 2, bk8 = (t & 3) * 8;    // 64 cols x 4 thr x 8 k

    u16x4 a0 = *(const u16x4*)(A + (size_t)(r0 + arow) * K + a4);
    bf16x8 b0 = *(const bf16x8*)(WT + (size_t)(c0 + bcol) * K + bk8);

    const int nk = K >> 5;
    for (int ki = 0; ki < nk; ++ki) {
        const int cur = ki & 1;
        *(u16x4*)&As[cur][arow][a4] = a0;
        *(bf16x8*)&Bs[cur][bcol][bk8] = b0;
        if (ki + 1 < nk) {
            const int k0 = (ki + 1) * 32;
            a0 = *(const u16x4*)(A + (size_t)(r0 + arow) * K + k0 + a4);
            b0 = *(const bf16x8*)(WT + (size_t)(c0 + bcol) * K + k0 + bk8);
        }
        __syncthreads();
        bf16x8 af = *(const bf16x8*)&As[cur][16 * (w & 1) + li][g * 8];
#pragma unroll
        for (int sub = 0; sub < 2; ++sub) {
            bf16x8 bfr = *(const bf16x8*)&Bs[cur][(w >> 1) * 32 + sub * 16 + li][g * 8];
            acc[sub] = __builtin_amdgcn_mfma_f32_16x16x32_bf16(af, bfr, acc[sub], 0, 0, 0);
        }
    }
#pragma unroll
    for (int sub = 0; sub < 2; ++sub) {
        int col = c0 + (w >> 1) * 32 + sub * 16 + li;
        float bv = bias ? bias[col] : 0.f;
#pragma unroll
        for (int r = 0; r < 4; ++r) {
            int row = r0 + 16 * (w & 1) + g * 4 + r;
            float o = acc[sub][r] + bv;
            if (relu) o = fmaxf(o, 0.f);
            if (Ch) Ch[(size_t)row * Nc + col] = f_to_bf16(o);
            else    Cf[(size_t)row * Nc + col] = o;
        }
    }
}

// ---------------------------------------------------------------------------
// qrk[b,h,n,rel] = q_n . relk[rel]  (q pre-scaled in Wq cast). Block=(chunk,h,b).
__global__ __launch_bounds__(256) void qrk_kernel(
    const unsigned short* __restrict__ qkvh, const float* __restrict__ relk_g,
    unsigned short* __restrict__ qrkg)
{
    const int n0 = blockIdx.x * 64, h = blockIdx.y, b = blockIdx.z;
    const int t = threadIdx.x, lane = t & 63, w = t >> 6;
    const int g = lane >> 4, li = lane & 15;
    const int qrow = 16 * w + g * 4;

    __shared__ unsigned short relk_s[100][40];
    for (int i = t; i < 400; i += 256) {
        int rr = i >> 2, d8 = (i & 3) * 8;
        const float* sp = relk_g + rr * 32 + d8;
        *(bf16x8*)&relk_s[rr][d8] = pack8(*(const float4*)sp, *(const float4*)(sp + 4));
    }
    bf16x8 qf = *(const bf16x8*)(qkvh + (size_t)(b * NN + n0 + 16 * w + li) * 768 + h * 32 + g * 8);
    __syncthreads();
#pragma unroll
    for (int rc = 0; rc < 7; ++rc) {
        bf16x8 bb = *(const bf16x8*)&relk_s[rc * 16 + li][g * 8];
        f32x4 s = __builtin_amdgcn_mfma_f32_16x16x32_bf16(qf, bb, (f32x4){0.f,0.f,0.f,0.f}, 0, 0, 0);
        int col = rc * 16 + li;
        if (col < 100) {
#pragma unroll
            for (int r = 0; r < 4; ++r)
                qrkg[((size_t)(b * 8 + h) * NN + n0 + qrow + r) * 100 + col] = f_to_bf16(s[r]);
        }
    }
}

// ---------------------------------------------------------------------------
// Attention: 32-q-row chunks, 4 waves = 2 q-waves x 2 m-halves. LDS 34.6 KB ->
// 4 blocks/CU resident = exactly the 4 blocks/CU of work (no straggler phase).
// wrel/qrk shared in-block (atomics); wrel@relv added by m-half 0 only.
__global__ __launch_bounds__(256, 4) void attn_mfma(
    const unsigned short* __restrict__ qkvh,  // [4096][768] bf16, q pre-scaled
    const short* __restrict__ rel16,
    const unsigned short* __restrict__ qrkg,  // [64][512][100] bf16
    const float* __restrict__ relv_g,
    float* __restrict__ zpart, float* __restrict__ smpart)
{
    const int p = blockIdx.x;            // 0..1023
    const int cx = p & 7, k = p >> 3;    // k 0..127
    const int sg = cx * 16 + (k >> 3);   // (b, chunk32) slice 0..127, XCD-grouped
    const int h  = k & 7;
    const int b = sg >> 4, chunk = sg & 15;
    const int n0 = chunk * 32;

    const int t = threadIdx.x;
    const int lane = t & 63, w = t >> 6;
    const int qw = w & 1, mhalf = w >> 1;
    const int g = lane >> 4, li = lane & 15;
    const int qrow = 16 * qw + g * 4;    // +r, 0..31
    const int mbase = mhalf * 256;

    __shared__ float wrel[32][100];            // 12800 B (shared, atomics)
    __shared__ unsigned short qrk_lds[32][100];// 6400 B
    __shared__ union {
        unsigned short relvT[32][136];         // 8704 B (epilogue)
        struct {
            unsigned short v_t[2][2][32][40];  // [mhalf][buf][d][m] 10240 B
            unsigned short p_s[4][16][40];     // per-wave 5120 B
        } mn;                                  // 15360 B
    } u;                                       // total 34560 B -> 4 blocks/CU

    // prologue: zero wrel, bulk-stage qrk rows (32 x 50 dwords), load Q frag
    for (int i = t; i < 3200; i += 256) ((float*)wrel)[i] = 0.f;
    {
        const unsigned short* qsrc = qrkg + ((size_t)(b * 8 + h) * NN + n0) * 100;
        for (int i = t; i < 1600; i += 256) {
            int row = i / 50, off = (i - row * 50) * 2;
            *(unsigned int*)&qrk_lds[row][off] =
                *(const unsigned int*)(qsrc + (size_t)row * 100 + off);
        }
    }
    bf16x8 qf = *(const bf16x8*)(qkvh + (size_t)(b * NN + n0 + 16 * qw + li) * 768 + h * 32 + g * 8);

    const short* relrow[4];
#pragma unroll
    for (int r = 0; r < 4; ++r)
        relrow[r] = rel16 + ((size_t)b * NN + n0 + qrow + r) * NN;
    const int th = t & 127;                    // thread id within m-half pair
    const int vm = th & 31, vdg = th >> 5;     // V stage: row vm, d-group vdg*8
    const size_t kRB = (size_t)(b * NN) * 768 + 256 + h * 32 + g * 8;
    const size_t vRB = (size_t)(b * NN) * 768 + 512 + h * 32 + vdg * 8;

    bf16x8 kbuf[2][2]; bf16x8 vbuf[2]; short rbuf[2][8];
#pragma unroll
    for (int i = 0; i < 8; ++i)
        rbuf[0][i] = relrow[i & 3][mbase + (i >> 2) * 16 + li];
    kbuf[0][0] = *(const bf16x8*)(qkvh + kRB + (size_t)(mbase + li) * 768);
    kbuf[0][1] = *(const bf16x8*)(qkvh + kRB + (size_t)(mbase + 16 + li) * 768);
    vbuf[0]    = *(const bf16x8*)(qkvh + vRB + (size_t)(mbase + vm) * 768);

    float smacc[4] = {0.f, 0.f, 0.f, 0.f};
    f32x4 zf[2];
    zf[0] = (f32x4){0.f,0.f,0.f,0.f};
    zf[1] = (f32x4){0.f,0.f,0.f,0.f};

    // main loop: 8 tiles of 32 m, one barrier per tile
#pragma unroll
    for (int tt = 0; tt < 8; ++tt) {
        const int cur = tt & 1, nxt = cur ^ 1;
        {   // write own half's V tile transposed [d][m]
            bf16x8 vv = vbuf[cur];
#pragma unroll
            for (int j = 0; j < 8; ++j)
                u.mn.v_t[mhalf][cur][vdg * 8 + j][vm] = (unsigned short)vv[j];
        }
        if (tt + 1 < 8) {
            const int m0n = mbase + (tt + 1) * 32;
#pragma unroll
            for (int i = 0; i < 8; ++i)
                rbuf[nxt][i] = relrow[i & 3][m0n + (i >> 2) * 16 + li];
        }
        __syncthreads();
        bf16x8 kf0 = kbuf[cur][0], kf1 = kbuf[cur][1];
        if (tt + 1 < 8) {   // issue next K/V early (hide under compute)
            const int m0n = mbase + (tt + 1) * 32;
            kbuf[nxt][0] = *(const bf16x8*)(qkvh + kRB + (size_t)(m0n + li) * 768);
            kbuf[nxt][1] = *(const bf16x8*)(qkvh + kRB + (size_t)(m0n + 16 + li) * 768);
            vbuf[nxt]    = *(const bf16x8*)(qkvh + vRB + (size_t)(m0n + vm) * 768);
        }
        f32x4 s0 = __builtin_amdgcn_mfma_f32_16x16x32_bf16(qf, kf0, (f32x4){0.f,0.f,0.f,0.f}, 0, 0, 0);
        f32x4 s1 = __builtin_amdgcn_mfma_f32_16x16x32_bf16(qf, kf1, (f32x4){0.f,0.f,0.f,0.f}, 0, 0, 0);
        float pr[8];
#pragma unroll
        for (int i = 0; i < 8; ++i) {
            const int r = i & 3;
            const int rl = rbuf[cur][i];
            const float qadd = bf16_to_f(qrk_lds[qrow + r][rl < 0 ? 0 : rl]);
            const float sv = ((i >> 2) ? s1[r] : s0[r]) + qadd;
            float pv = 0.f;
            if (rl >= 0) {
                pv = __expf(fminf(sv, 50.f));
                atomicAdd(&wrel[qrow + r][rl], pv);
            }
            smacc[r] += pv;
            pr[i] = pv;
        }
#pragma unroll
        for (int i = 0; i < 8; ++i)
            u.mn.p_s[w][g * 4 + (i & 3)][(i >> 2) * 16 + li] = f_to_bf16(pr[i]);
        asm volatile("s_waitcnt lgkmcnt(0)" ::: "memory");
        __builtin_amdgcn_sched_barrier(0);
        bf16x8 pa = *(const bf16x8*)&u.mn.p_s[w][li][g * 8];
#pragma unroll
        for (int dc = 0; dc < 2; ++dc) {
            bf16x8 vb = *(const bf16x8*)&u.mn.v_t[mhalf][cur][dc * 16 + li][g * 8];
            zf[dc] = __builtin_amdgcn_mfma_f32_16x16x32_bf16(pa, vb, zf[dc], 0, 0, 0);
        }
    }
    __syncthreads();   // wrel atomics + p_s reads complete

    // epilogue: stage relv^T (shared); wrel @ relv added by m-half 0 only
    for (int i = t; i < 32 * 36; i += 256) {
        int d = i / 36, c = 100 + (i - (i / 36) * 36);
        u.relvT[d][c] = 0;
    }
    for (int i = t; i < 400; i += 256) {
        int rr2 = i >> 2, d8 = (i & 3) * 8;
        const float* sp = relv_g + rr2 * 32 + d8;
        float4 s0 = *(const float4*)sp, s1 = *(const float4*)(sp + 4);
        u.relvT[d8 + 0][rr2] = f_to_bf16(s0.x);
        u.relvT[d8 + 1][rr2] = f_to_bf16(s0.y);
        u.relvT[d8 + 2][rr2] = f_to_bf16(s0.z);
        u.relvT[d8 + 3][rr2] = f_to_bf16(s0.w);
        u.relvT[d8 + 4][rr2] = f_to_bf16(s1.x);
        u.relvT[d8 + 5][rr2] = f_to_bf16(s1.y);
        u.relvT[d8 + 6][rr2] = f_to_bf16(s1.z);
        u.relvT[d8 + 7][rr2] = f_to_bf16(s1.w);
    }
    __syncthreads();
    if (mhalf == 0) {
#pragma unroll
        for (int kc = 0; kc < 4; ++kc) {
            const int kbase = kc * 32 + g * 8;
            const float* wp = &wrel[16 * qw + li][0];
            bf16x8 af;
#pragma unroll
            for (int j = 0; j < 8; ++j) {
                int id = kbase + j;
                float val = (id < 100) ? wp[id] : 0.f;
                af[j] = (short)f_to_bf16(val);
            }
#pragma unroll
            for (int dc = 0; dc < 2; ++dc) {
                bf16x8 vbr = *(const bf16x8*)&u.relvT[dc * 16 + li][kbase];
                zf[dc] = __builtin_amdgcn_mfma_f32_16x16x32_bf16(af, vbr, zf[dc], 0, 0, 0);
            }
        }
    }
#pragma unroll
    for (int r = 0; r < 4; ++r) {
        smacc[r] += __shfl_xor(smacc[r], 1, 64);
        smacc[r] += __shfl_xor(smacc[r], 2, 64);
        smacc[r] += __shfl_xor(smacc[r], 4, 64);
        smacc[r] += __shfl_xor(smacc[r], 8, 64);
    }
#pragma unroll
    for (int r = 0; r < 4; ++r) {
        const int row = b * NN + n0 + qrow + r;
        size_t ob = (size_t)mhalf * 1048576 + (size_t)row * 256 + h * 32;
#pragma unroll
        for (int dc = 0; dc < 2; ++dc)
            zpart[ob + dc * 16 + li] = zf[dc][r];
        if (li == 0)
            smpart[(size_t)mhalf * 32768 + (size_t)row * 8 + h] = smacc[r];
    }
}

// ---------------------------------------------------------------------------
__global__ __launch_bounds__(256) void combine_kernel(
    const float* __restrict__ zpart, const float* __restrict__ smpart,
    unsigned short* __restrict__ zbf)
{
    const int t = threadIdx.x;
    const int wi = t >> 6, lane = t & 63;
    const int row = blockIdx.x * 4 + wi;
    const int h = lane >> 3;
    float den = 0.f;
    float4 acc = make_float4(0.f, 0.f, 0.f, 0.f);
#pragma unroll
    for (int s = 0; s < 2; ++s) {
        den += smpart[(size_t)s * 32768 + (size_t)row * 8 + h];
        float4 v = *(const float4*)(zpart + (size_t)s * 1048576 + (size_t)row * 256 + lane * 4);
        acc.x += v.x; acc.y += v.y; acc.z += v.z; acc.w += v.w;
    }
    const float inv = 1.f / den;
    u16x4 oh;
    oh[0] = f_to_bf16(acc.x * inv);
    oh[1] = f_to_bf16(acc.y * inv);
    oh[2] = f_to_bf16(acc.z * inv);
    oh[3] = f_to_bf16(acc.w * inv);
    *(u16x4*)(zbf + (size_t)row * 256 + lane * 4) = oh;
}

// ---------------------------------------------------------------------------
__global__ __launch_bounds__(256) void ln_kernel(
    const float* __restrict__ xin, const float* __restrict__ y,
    const float* __restrict__ g, const float* __restrict__ bsh,
    float* __restrict__ xout, unsigned short* __restrict__ xh)
{
    const int t = threadIdx.x;
    const int w = t >> 6, lane = t & 63;
    const size_t row = (size_t)blockIdx.x * 4 + w;
    const float4 xv = *(const float4*)(xin + row * 256 + lane * 4);
    const float4 yv = *(const float4*)(y + row * 256 + lane * 4);
    float4 sv;
    sv.x = xv.x + yv.x; sv.y = xv.y + yv.y; sv.z = xv.z + yv.z; sv.w = xv.w + yv.w;
    float sum = sv.x + sv.y + sv.z + sv.w;
    float sq  = sv.x * sv.x + sv.y * sv.y + sv.z * sv.z + sv.w * sv.w;
#pragma unroll
    for (int off = 1; off < 64; off <<= 1) {
        sum += __shfl_xor(sum, off, 64);
        sq  += __shfl_xor(sq, off, 64);
    }
    const float mu = sum * (1.f / 256.f);
    const float var = sq * (1.f / 256.f) - mu * mu;
    const float rs = rsqrtf(var + 1e-5f);
    const float4 gv = *(const float4*)(g + lane * 4);
    const float4 bv = *(const float4*)(bsh + lane * 4);
    float4 o;
    o.x = (sv.x - mu) * rs * gv.x + bv.x;
    o.y = (sv.y - mu) * rs * gv.y + bv.y;
    o.z = (sv.z - mu) * rs * gv.z + bv.z;
    o.w = (sv.w - mu) * rs * gv.w + bv.w;
    *(float4*)(xout + row * 256 + lane * 4) = o;
    u16x4 oh;
    oh[0] = f_to_bf16(o.x); oh[1] = f_to_bf16(o.y);
    oh[2] = f_to_bf16(o.z); oh[3] = f_to_bf16(o.w);
    *(u16x4*)(xh + row * 256 + lane * 4) = oh;
}

// ---------------------------------------------------------------------------
extern "C" void kernel_launch(void* const* d_in, const int* in_sizes, int n_in,
                              void* d_out, int out_size, void* d_ws, size_t ws_size,
                              hipStream_t stream)
{
    (void)in_sizes; (void)n_in; (void)out_size;
    const int*   tok   = (const int*)d_in[0];
    const int*   rel   = (const int*)d_in[1];
    const void*  mask  = d_in[2];
    const float* embed = (const float*)d_in[3];
    const float* W_in  = (const float*)d_in[4];
    const float* b_in  = (const float*)d_in[5];
    const float* Wq    = (const float*)d_in[6];
    const float* Wk    = (const float*)d_in[7];
    const float* Wv    = (const float*)d_in[8];
    const float* Wo    = (const float*)d_in[9];
    const float* ln1g  = (const float*)d_in[10];
    const float* ln1b  = (const float*)d_in[11];
    const float* ln2g  = (const float*)d_in[12];
    const float* ln2b  = (const float*)d_in[13];
    const float* W1    = (const float*)d_in[14];
    const float* b1    = (const float*)d_in[15];
    const float* W2    = (const float*)d_in[16];
    const float* b2    = (const float*)d_in[17];
    const float* relk  = (const float*)d_in[18];
    const float* relv  = (const float*)d_in[19];
    const float* Wout  = (const float*)d_in[20];
    const float* bout  = (const float*)d_in[21];
    float* out = (float*)d_out;
    const float scale = 0.17677669529663687f;

    float* ws = (float*)d_ws;
    float*          x     = ws;                                   // 1M f32
    unsigned short* xh    = (unsigned short*)(ws + 1048576);      // 0.5M
    unsigned short* zbf   = (unsigned short*)(ws + 1572864);      // 0.5M
    float*          zo    = ws + 2097152;                         // 1M
    unsigned short* qkvh  = (unsigned short*)(ws + 3145728);      // 1.5M
    unsigned short* hbh   = (unsigned short*)(ws + 4718592);      // 2M
    float*          zpart = ws + 6815744;                         // 2M
    float*          smpart= ws + 8912896;                         // 64K
    unsigned short* qrkg  = (unsigned short*)(ws + 8978432);      // 1.6384M
    int*            flag  = (int*)(ws + 10616832);
    unsigned short* wt    = (unsigned short*)(ws + 10616848);

    const size_t wsf = ws_size >> 2;
    const bool tierA = wsf >= 13271100;   // all-layer weight cache + dedicated rel16
    short* rel16 = tierA ? (short*)(ws + 12222480) : (short*)hbh;

    detect_mask_kernel<<<1, 256, 0, stream>>>((const unsigned char*)mask, flag);
    embed_proj_kernel<<<512, 256, 0, stream>>>(tok, embed, W_in, b_in, x, xh);
    if (tierA) {
        prep_rel16<<<4096, 256, 0, stream>>>(rel, mask, flag, rel16);
        tcast256<<<dim3(8, 8, 17), 256, 0, stream>>>(Wq, Wk, Wv, Wo, Wout, wt, 4, scale);
        tcastKN<<<dim3(32, 8, 4), 256, 0, stream>>>(W1, wt + 262144, 256, 1024, 262144, 786432);
        tcastKN<<<dim3(8, 32, 4), 256, 0, stream>>>(W2, wt + 524288, 1024, 256, 262144, 786432);
    }

    for (int l = 0; l < 4; ++l) {
        unsigned short* wl = tierA ? wt + (size_t)l * 786432 : wt;
        if (!tierA) {
            prep_rel16<<<4096, 256, 0, stream>>>(rel, mask, flag, rel16);
            tcast256<<<dim3(8, 8, 4), 256, 0, stream>>>(
                Wq + (size_t)l * 65536, Wk + (size_t)l * 65536,
                Wv + (size_t)l * 65536, Wo + (size_t)l * 65536, Wout, wt, 1, scale);
            tcastKN<<<dim3(32, 8, 1), 256, 0, stream>>>(W1 + (size_t)l * 262144, wt + 262144, 256, 1024, 0, 0);
            tcastKN<<<dim3(8, 32, 1), 256, 0, stream>>>(W2 + (size_t)l * 262144, wt + 524288, 1024, 256, 0, 0);
        }
        // fused QKV (q pre-scaled): xh @ WqkvT -> qkvh bf16
        gemm_bf16_64<<<dim3(12, 64), 256, 0, stream>>>(xh, wl, nullptr, nullptr, qkvh,
                                                       NTOK, 256, 768, 0);
        qrk_kernel<<<dim3(8, 8, 8), 256, 0, stream>>>(qkvh, relk, qrkg);
        attn_mfma<<<1024, 256, 0, stream>>>(qkvh, rel16, qrkg, relv, zpart, smpart);
        combine_kernel<<<1024, 256, 0, stream>>>(zpart, smpart, zbf);
        gemm_bf16_32<<<dim3(4, 128), 256, 0, stream>>>(zbf, wl + 196608, nullptr, zo, nullptr,
                                                       NTOK, 256, 256, 0);
        ln_kernel<<<1024, 256, 0, stream>>>(x, zo, ln1g + l * 256, ln1b + l * 256, x, xh);
        gemm_bf16_64<<<dim3(16, 64), 256, 0, stream>>>(xh, wl + 262144, b1 + l * 1024, nullptr, hbh,
                                                       NTOK, 256, 1024, 1);
        gemm_bf16_32<<<dim3(4, 128), 256, 0, stream>>>(hbh, wl + 524288, b2 + l * 256, zo, nullptr,
                                                       NTOK, 1024, 256, 0);
        ln_kernel<<<1024, 256, 0, stream>>>(x, zo, ln2g + l * 256, ln2b + l * 256, x, xh);
    }
    unsigned short* woutT = wt;
    if (tierA) {
        woutT = wt + (size_t)4 * 786432;
    } else {
        tcast256<<<dim3(8, 8, 1), 256, 0, stream>>>(Wq, Wk, Wv, Wo, Wout, wt, 0, scale);
    }
    gemm_bf16_32<<<dim3(4, 128), 256, 0, stream>>>(xh, woutT, bout, out, nullptr,
                                                   NTOK, 256, 256, 0);
}